// Round 2
// baseline (477.204 us; speedup 1.0000x reference)
//
#include <hip/hip_runtime.h>

// TransformerBlock: x = x + attn(rms(x)); x = x + mlp(rms(x))
// B=2, S=2048, D=1024, H=16, dh=64, EXP=4. Inputs/outputs fp32; internal bf16 MFMA.

typedef __attribute__((ext_vector_type(8))) short short8;   // 8 x bf16 = 4 VGPR
typedef __attribute__((ext_vector_type(4))) float floatx4;  // MFMA 16x16 acc

#define EPI_NONE 0
#define EPI_RES  1
#define EPI_GATE 2
#define EPI_QKV  3

#define QSCALE 0.1803368801f   // 0.125 * log2(e): folded into Q so softmax is base-2

__device__ __forceinline__ float b2f(unsigned short u) {
  union { unsigned int i; float f; } c; c.i = ((unsigned int)u) << 16; return c.f;
}
__device__ __forceinline__ unsigned short f2b(float f) {
  union { float f; unsigned int u; } c; c.f = f;
  unsigned int r = 0x7fffu + ((c.u >> 16) & 1u);
  return (unsigned short)((c.u + r) >> 16);
}
__device__ __forceinline__ unsigned int f2b2(float a, float b) {
  return (unsigned int)f2b(a) | ((unsigned int)f2b(b) << 16);
}

__device__ __forceinline__ void load_lds16(const void* g, void* l) {
  __builtin_amdgcn_global_load_lds(
      (const __attribute__((address_space(1))) unsigned int*)g,
      (__attribute__((address_space(3))) unsigned int*)l, 16, 0, 0);
}

// ---------------- fused fp32 -> bf16 convert of all 5 weights ----------------
// float4 units: wq 786432, wo 262144, wu/wg/wd 1048576 each; total 4194304.
__global__ __launch_bounds__(256)
void cvt_all_kernel(const float* __restrict__ wq, const float* __restrict__ wo,
                    const float* __restrict__ wu, const float* __restrict__ wg,
                    const float* __restrict__ wd,
                    unsigned short* __restrict__ oq, unsigned short* __restrict__ oo,
                    unsigned short* __restrict__ ou, unsigned short* __restrict__ og,
                    unsigned short* __restrict__ od) {
  int i = blockIdx.x * 256 + threadIdx.x;
  const float* src; unsigned short* dst; int k;
  if (i < 786432)        { src = wq; dst = oq; k = i; }
  else if (i < 1048576)  { src = wo; dst = oo; k = i - 786432; }
  else if (i < 2097152)  { src = wu; dst = ou; k = i - 1048576; }
  else if (i < 3145728)  { src = wg; dst = og; k = i - 2097152; }
  else                   { src = wd; dst = od; k = i - 3145728; }
  float4 v = ((const float4*)src)[k];
  ushort4 o;
  o.x = f2b(v.x); o.y = f2b(v.y); o.z = f2b(v.z); o.w = f2b(v.w);
  ((ushort4*)dst)[k] = o;
}

// ---------------- RMSNorm: one block per row of 1024, fp32 in -> bf16 out ----------------
__global__ __launch_bounds__(256)
void rmsnorm_kernel(const float* __restrict__ x,
                    const float* __restrict__ scale,
                    unsigned short* __restrict__ y) {
  const int row = blockIdx.x;
  const int tid = threadIdx.x;
  const int base = row * 1024 + tid * 4;
  float4 v = *(const float4*)(x + base);
  float ss = v.x*v.x + v.y*v.y + v.z*v.z + v.w*v.w;
#pragma unroll
  for (int d = 32; d > 0; d >>= 1) ss += __shfl_down(ss, d);
  __shared__ float red[4];
  const int wave = tid >> 6, lane = tid & 63;
  if (lane == 0) red[wave] = ss;
  __syncthreads();
  float tot = red[0] + red[1] + red[2] + red[3];
  float rs = rsqrtf(tot * (1.0f/1024.0f) + 1e-6f);
  float4 sv = *(const float4*)(scale + tid * 4);
  ushort4 o;
  o.x = f2b(v.x * rs * sv.x);
  o.y = f2b(v.y * rs * sv.y);
  o.z = f2b(v.z * rs * sv.z);
  o.w = f2b(v.w * rs * sv.w);
  *(ushort4*)(y + base) = o;
}

// ---------------- RMSNorm + residual reduce: x1 = x + p0 + p1; y = rms(x1) ----------------
__global__ __launch_bounds__(256)
void rmsnorm_res2_kernel(const float* __restrict__ x,
                         const float* __restrict__ p0,
                         const float* __restrict__ p1,
                         const float* __restrict__ scale,
                         float* __restrict__ x1,
                         unsigned short* __restrict__ y) {
  const int row = blockIdx.x;
  const int tid = threadIdx.x;
  const int base = row * 1024 + tid * 4;
  float4 a = *(const float4*)(x + base);
  float4 b = *(const float4*)(p0 + base);
  float4 c = *(const float4*)(p1 + base);
  float4 v;
  v.x = a.x + b.x + c.x; v.y = a.y + b.y + c.y;
  v.z = a.z + b.z + c.z; v.w = a.w + b.w + c.w;
  *(float4*)(x1 + base) = v;
  float ss = v.x*v.x + v.y*v.y + v.z*v.z + v.w*v.w;
#pragma unroll
  for (int d = 32; d > 0; d >>= 1) ss += __shfl_down(ss, d);
  __shared__ float red[4];
  const int wave = tid >> 6, lane = tid & 63;
  if (lane == 0) red[wave] = ss;
  __syncthreads();
  float tot = red[0] + red[1] + red[2] + red[3];
  float rs = rsqrtf(tot * (1.0f/1024.0f) + 1e-6f);
  float4 sv = *(const float4*)(scale + tid * 4);
  ushort4 o;
  o.x = f2b(v.x * rs * sv.x);
  o.y = f2b(v.y * rs * sv.y);
  o.z = f2b(v.z * rs * sv.z);
  o.w = f2b(v.w * rs * sv.w);
  *(ushort4*)(y + base) = o;
}

// ---------------- final reduce: outp = x1 + outp + p1 (outp holds slice-0 partial) ----------------
__global__ __launch_bounds__(256)
void reduce_out_kernel(const float* __restrict__ x1,
                       const float* __restrict__ p1,
                       float* outp) {
  int i = blockIdx.x * 256 + threadIdx.x;
  float4 a = ((const float4*)x1)[i];
  float4 b = ((const float4*)p1)[i];
  float4 c = ((float4*)outp)[i];
  float4 v;
  v.x = a.x + b.x + c.x; v.y = a.y + b.y + c.y;
  v.z = a.z + b.z + c.z; v.w = a.w + b.w + c.w;
  ((float4*)outp)[i] = v;
}

// ---------------- GEMM: C[M,ldc] = A[M,K] @ B[N,K]^T (m97 structure) ----------------
// EPI_QKV: Q cols (<1024) scaled by QSCALE; V cols (>=2048) redirected to VT[b,h,d][s].
template<int EPI, typename OutT, typename ResT>
__global__ __launch_bounds__(256)
void gemm_bt(const unsigned short* __restrict__ A,
             const unsigned short* __restrict__ B,
             OutT* C, const ResT* R, unsigned short* VT,
             int M, int N, int K, int ldc) {
  __shared__ __align__(16) unsigned short As[128 * 32];
  __shared__ __align__(16) unsigned short Bs[128 * 32];
  const int tid = threadIdx.x;
  const int wave = tid >> 6;
  const int lane = tid & 63;
  const int m0 = blockIdx.y * 128;
  const int n0 = blockIdx.x * 128;
  const int wm = (wave & 1) * 64;
  const int wn = (wave >> 1) * 64;
  const int frow = lane & 15;
  const int fk = (lane >> 4) * 8;

  floatx4 acc[4][4];
#pragma unroll
  for (int i = 0; i < 4; ++i)
#pragma unroll
    for (int j = 0; j < 4; ++j) acc[i][j] = (floatx4){0.f, 0.f, 0.f, 0.f};

  const int srow = lane >> 2;
  const int scol = (lane & 3) * 8;
  const unsigned short* Ag  = A + (size_t)(m0 + wave * 16 + srow) * K + scol;
  const unsigned short* Ag2 = A + (size_t)(m0 + (wave + 4) * 16 + srow) * K + scol;
  const unsigned short* Bg  = B + (size_t)(n0 + wave * 16 + srow) * K + scol;
  const unsigned short* Bg2 = B + (size_t)(n0 + (wave + 4) * 16 + srow) * K + scol;

  for (int k0 = 0; k0 < K; k0 += 32) {
    __syncthreads();
    load_lds16(Ag + k0,  &As[wave * 512]);
    load_lds16(Ag2 + k0, &As[(wave + 4) * 512]);
    load_lds16(Bg + k0,  &Bs[wave * 512]);
    load_lds16(Bg2 + k0, &Bs[(wave + 4) * 512]);
    __syncthreads();
    short8 af[4], bf[4];
#pragma unroll
    for (int i = 0; i < 4; ++i) af[i] = *(const short8*)&As[(wm + 16*i + frow)*32 + fk];
#pragma unroll
    for (int j = 0; j < 4; ++j) bf[j] = *(const short8*)&Bs[(wn + 16*j + frow)*32 + fk];
#pragma unroll
    for (int i = 0; i < 4; ++i)
#pragma unroll
      for (int j = 0; j < 4; ++j)
        acc[i][j] = __builtin_amdgcn_mfma_f32_16x16x32_bf16(af[i], bf[j], acc[i][j], 0, 0, 0);
  }

  const int g4 = (lane >> 4) * 4;

  if constexpr (EPI == EPI_QKV) {
    if (n0 >= 2048) {
      // V tile: store transposed into VT[(b*16+h)*64+dd][s]
#pragma unroll
      for (int i = 0; i < 4; ++i) {
        const int row0 = m0 + wm + 16*i + g4;     // token index (r=0)
        const int b = row0 >> 11, s0 = row0 & 2047;
#pragma unroll
        for (int j = 0; j < 4; ++j) {
          const int col = n0 + wn + 16*j + frow;  // 2048..3071
          const int dg = col - 2048;
          const int rowv = (b << 10) + dg;        // (b*16+h)*64+dd == b*1024+dg
          ushort4 ov;
          ov.x = f2b(acc[i][j][0]);
          ov.y = f2b(acc[i][j][1]);
          ov.z = f2b(acc[i][j][2]);
          ov.w = f2b(acc[i][j][3]);
          *(ushort4*)(VT + (size_t)rowv * 2048 + s0) = ov;
        }
      }
      return;
    }
  }

  const float qs = (EPI == EPI_QKV && n0 < 1024) ? QSCALE : 1.0f;
#pragma unroll
  for (int i = 0; i < 4; ++i) {
#pragma unroll
    for (int r = 0; r < 4; ++r) {
      const int row = m0 + wm + 16*i + g4 + r;
#pragma unroll
      for (int j = 0; j < 4; ++j) {
        const int col = n0 + wn + 16*j + frow;
        const size_t idx = (size_t)row * ldc + col;
        float v = acc[i][j][r];
        if constexpr (EPI == EPI_RES) {
          v += (float)R[idx];
        } else if constexpr (EPI == EPI_GATE) {
          float up = b2f((unsigned short)R[idx]);
          v = up * (v / (1.f + __expf(-v)));
        } else if constexpr (EPI == EPI_QKV) {
          v *= qs;
        }
        if constexpr (sizeof(OutT) == 4) C[idx] = v;
        else                             C[idx] = f2b(v);
      }
    }
  }
}

// ---------------- Split-K GEMM: P_z[M,N] = A[M, z*Ks : (z+1)*Ks] @ B^T slice ----------------
__global__ __launch_bounds__(256)
void gemm_bt_splitk(const unsigned short* __restrict__ A,
                    const unsigned short* __restrict__ B,
                    float* __restrict__ P0, float* __restrict__ P1,
                    int M, int N, int K, int Ks) {
  __shared__ __align__(16) unsigned short As[128 * 32];
  __shared__ __align__(16) unsigned short Bs[128 * 32];
  const int tid = threadIdx.x;
  const int wave = tid >> 6;
  const int lane = tid & 63;
  const int m0 = blockIdx.y * 128;
  const int n0 = blockIdx.x * 128;
  const int z = blockIdx.z;
  float* C = z ? P1 : P0;
  const int kbase = z * Ks;
  const int wm = (wave & 1) * 64;
  const int wn = (wave >> 1) * 64;
  const int frow = lane & 15;
  const int fk = (lane >> 4) * 8;

  floatx4 acc[4][4];
#pragma unroll
  for (int i = 0; i < 4; ++i)
#pragma unroll
    for (int j = 0; j < 4; ++j) acc[i][j] = (floatx4){0.f, 0.f, 0.f, 0.f};

  const int srow = lane >> 2;
  const int scol = (lane & 3) * 8;
  const unsigned short* Ag  = A + (size_t)(m0 + wave * 16 + srow) * K + kbase + scol;
  const unsigned short* Ag2 = A + (size_t)(m0 + (wave + 4) * 16 + srow) * K + kbase + scol;
  const unsigned short* Bg  = B + (size_t)(n0 + wave * 16 + srow) * K + kbase + scol;
  const unsigned short* Bg2 = B + (size_t)(n0 + (wave + 4) * 16 + srow) * K + kbase + scol;

  for (int k0 = 0; k0 < Ks; k0 += 32) {
    __syncthreads();
    load_lds16(Ag + k0,  &As[wave * 512]);
    load_lds16(Ag2 + k0, &As[(wave + 4) * 512]);
    load_lds16(Bg + k0,  &Bs[wave * 512]);
    load_lds16(Bg2 + k0, &Bs[(wave + 4) * 512]);
    __syncthreads();
    short8 af[4], bf[4];
#pragma unroll
    for (int i = 0; i < 4; ++i) af[i] = *(const short8*)&As[(wm + 16*i + frow)*32 + fk];
#pragma unroll
    for (int j = 0; j < 4; ++j) bf[j] = *(const short8*)&Bs[(wn + 16*j + frow)*32 + fk];
#pragma unroll
    for (int i = 0; i < 4; ++i)
#pragma unroll
      for (int j = 0; j < 4; ++j)
        acc[i][j] = __builtin_amdgcn_mfma_f32_16x16x32_bf16(af[i], bf[j], acc[i][j], 0, 0, 0);
  }

  const int g4 = (lane >> 4) * 4;
#pragma unroll
  for (int i = 0; i < 4; ++i)
#pragma unroll
    for (int r = 0; r < 4; ++r) {
      const int row = m0 + wm + 16*i + g4 + r;
#pragma unroll
      for (int j = 0; j < 4; ++j) {
        const int col = n0 + wn + 16*j + frow;
        C[(size_t)row * N + col] = acc[i][j][r];
      }
    }
}

// ================= 256x(128out) 8-phase up+gate GEMM (m201 template, T1+T2+T3+T4+T5) =======
// A [4096,1024] bf16, Bu/Bg [4096,1024] bf16; C[row*4096+col] = up * silu(gate), bf16.
// BM=256, BK=64, 8 waves (2M x 4N), per-wave 128 rows x 32 up-cols (+32 gate).
// LDS 128 KiB: A[q][h] at (q*2+h)*8192 ushorts, B[q][h] at 32768 + (q*2+h)*8192.
//   B-half0 = w_up rows [bx*128,+128), B-half1 = w_gate rows (same out cols!).
// Swizzle: LDS(row, g) holds global granule g^(row&7); read XOR matches (both-sides).
// Stage slots: ph1:(t+1).A1  ph2-5:(t+2).{A0,B0,B1,A1}  ph6-8:(t+3).{A0,B0,B1}.
// vmcnt(6) (=3 half-tiles in flight) only at ph4/ph8, before the closing barrier.

#define A_OFF(q,h) (((q)*2+(h))*8192)
#define B_OFF(q,h) (32768 + ((q)*2+(h))*8192)

#define GBAR() __builtin_amdgcn_s_barrier()
#define WLG()  asm volatile("s_waitcnt lgkmcnt(0)" ::: "memory")
#define WVM(N) asm volatile("s_waitcnt vmcnt(" #N ")" ::: "memory")

#define STAGE(LB, SRC, T) do {                                               \
    const unsigned short* _s = (SRC) + (size_t)r0 * 1024 + (T) * 64 + gs;    \
    load_lds16(_s,             &lds[(LB) + wave * 512]);                     \
    load_lds16(_s + 64 * 1024, &lds[(LB) + 4096 + wave * 512]);              \
  } while (0)

#define LDA4(dst, q, h) do {                                                 \
    const unsigned short* _b = &lds[A_OFF(q,h) + arow];                      \
    _Pragma("unroll")                                                        \
    for (int _i = 0; _i < 4; ++_i) {                                         \
      dst[_i][0] = *(const short8*)(_b + _i * 1024 + g0);                    \
      dst[_i][1] = *(const short8*)(_b + _i * 1024 + g1);                    \
    }                                                                        \
  } while (0)

#define LDB2(dst, q, h) do {                                                 \
    const unsigned short* _b = &lds[B_OFF(q,h) + brow];                      \
    _Pragma("unroll")                                                        \
    for (int _j = 0; _j < 2; ++_j) {                                         \
      dst[_j][0] = *(const short8*)(_b + _j * 1024 + g0);                    \
      dst[_j][1] = *(const short8*)(_b + _j * 1024 + g1);                    \
    }                                                                        \
  } while (0)

#define MMQ(aa, bb, IO, JO) do {                                             \
    _Pragma("unroll")                                                        \
    for (int _i = 0; _i < 4; ++_i)                                           \
      _Pragma("unroll")                                                      \
      for (int _j = 0; _j < 2; ++_j) {                                       \
        acc[(IO)+_i][(JO)+_j] = __builtin_amdgcn_mfma_f32_16x16x32_bf16(     \
            aa[_i][0], bb[_j][0], acc[(IO)+_i][(JO)+_j], 0, 0, 0);           \
        acc[(IO)+_i][(JO)+_j] = __builtin_amdgcn_mfma_f32_16x16x32_bf16(     \
            aa[_i][1], bb[_j][1], acc[(IO)+_i][(JO)+_j], 0, 0, 0);           \
      }                                                                      \
  } while (0)

__global__ __launch_bounds__(512, 2)
void gemm256_upgate(const unsigned short* __restrict__ A,
                    const unsigned short* __restrict__ Bu,
                    const unsigned short* __restrict__ Bg,
                    unsigned short* __restrict__ C) {
  extern __shared__ __align__(16) unsigned short lds[];   // 65536 ushorts = 128 KiB
  const int tid  = threadIdx.x;
  const int wave = tid >> 6;
  const int lane = tid & 63;
  const int wr   = wave >> 2;       // 0..1  M-split
  const int wc   = wave & 3;        // 0..3  N-split
  const int frow = lane & 15;
  const int s4   = lane >> 4;       // 0..3

  // bijective XCD swizzle (512 % 8 == 0)
  const int orig = blockIdx.x;
  const int swz  = (orig & 7) * 64 + (orig >> 3);
  const int bx   = swz & 31;        // n-tile (out cols /128)
  const int by   = swz >> 5;        // m-tile (rows /256)
  const int m0   = by * 256;
  const int n0   = bx * 128;

  // fragment-read swizzled granule offsets (ushorts)
  const int f7 = frow & 7;
  const int g0 = ((0 + s4) ^ f7) * 8;    // kk=0
  const int g1 = ((4 + s4) ^ f7) * 8;    // kk=1
  const int arow = (wr * 64 + frow) * 64;   // + (i&3)*1024
  const int brow = (wc * 32 + frow) * 64;   // + (j&1)*1024

  // staging per-lane: LDS row r0 (+64 for round 1), pre-swizzled source granule
  const int r0 = wave * 8 + (lane >> 3);
  const int gs = ((lane & 7) ^ (lane >> 3)) * 8;

  const unsigned short* Asrc  = A  + (size_t)m0 * 1024;          // A-half1: +128*1024
  const unsigned short* B0src = Bu + (size_t)(bx * 128) * 1024;  // up rows
  const unsigned short* B1src = Bg + (size_t)(bx * 128) * 1024;  // gate rows (same cols)

  floatx4 acc[8][4];
#pragma unroll
  for (int i = 0; i < 8; ++i)
#pragma unroll
    for (int j = 0; j < 4; ++j) acc[i][j] = (floatx4){0.f, 0.f, 0.f, 0.f};

  // ---- prologue: tile0 {A0,B0,B1,A1}, vmcnt(4); tile1 {A0,B0,B1}, vmcnt(6) ----
  STAGE(A_OFF(0,0), Asrc, 0);
  STAGE(B_OFF(0,0), B0src, 0);
  STAGE(B_OFF(0,1), B1src, 0);
  STAGE(A_OFF(0,1), Asrc + 128 * 1024, 0);
  WVM(4);
  STAGE(A_OFF(1,0), Asrc, 1);
  STAGE(B_OFF(1,0), B0src, 1);
  STAGE(B_OFF(1,1), B1src, 1);
  WVM(6);
  GBAR();

  short8 af0[4][2], af1[4][2], bf0[2][2], bf1[2][2];

  for (int it = 0; it < 8; ++it) {
    const int t   = it * 2;                 // even tile -> buf0, odd -> buf1
    const int tn2 = (t + 2) & 15;           // wrapped (last iter stages are dead writes)
    const int tn3 = (t + 3) & 15;
    // ph1: (m0,n0) from buf0 | stage (t+1).A1
    LDA4(af0, 0, 0);
    LDB2(bf0, 0, 0);
    STAGE(A_OFF(1,1), Asrc + 128 * 1024, (t + 1) & 15);
    GBAR(); WLG();
    __builtin_amdgcn_s_setprio(1); MMQ(af0, bf0, 0, 0); __builtin_amdgcn_s_setprio(0);
    GBAR();
    // ph2: (m0,n1) | stage (t+2).A0
    LDB2(bf1, 0, 1);
    STAGE(A_OFF(0,0), Asrc, tn2);
    GBAR(); WLG();
    __builtin_amdgcn_s_setprio(1); MMQ(af0, bf1, 0, 2); __builtin_amdgcn_s_setprio(0);
    GBAR();
    // ph3: (m1,n0) | stage (t+2).B0
    LDA4(af1, 0, 1);
    STAGE(B_OFF(0,0), B0src, tn2);
    GBAR(); WLG();
    __builtin_amdgcn_s_setprio(1); MMQ(af1, bf0, 4, 0); __builtin_amdgcn_s_setprio(0);
    GBAR();
    // ph4: (m1,n1) | stage (t+2).B1 | vmcnt(6)
    STAGE(B_OFF(0,1), B1src, tn2);
    GBAR();
    __builtin_amdgcn_s_setprio(1); MMQ(af1, bf1, 4, 2); __builtin_amdgcn_s_setprio(0);
    WVM(6);
    GBAR();
    // ph5: (m0,n0) from buf1 | stage (t+2).A1
    LDA4(af0, 1, 0);
    LDB2(bf0, 1, 0);
    STAGE(A_OFF(0,1), Asrc + 128 * 1024, tn2);
    GBAR(); WLG();
    __builtin_amdgcn_s_setprio(1); MMQ(af0, bf0, 0, 0); __builtin_amdgcn_s_setprio(0);
    GBAR();
    // ph6: (m0,n1) | stage (t+3).A0
    LDB2(bf1, 1, 1);
    STAGE(A_OFF(1,0), Asrc, tn3);
    GBAR(); WLG();
    __builtin_amdgcn_s_setprio(1); MMQ(af0, bf1, 0, 2); __builtin_amdgcn_s_setprio(0);
    GBAR();
    // ph7: (m1,n0) | stage (t+3).B0
    LDA4(af1, 1, 1);
    STAGE(B_OFF(1,0), B0src, tn3);
    GBAR(); WLG();
    __builtin_amdgcn_s_setprio(1); MMQ(af1, bf0, 4, 0); __builtin_amdgcn_s_setprio(0);
    GBAR();
    // ph8: (m1,n1) | stage (t+3).B1 | vmcnt(6)
    STAGE(B_OFF(1,1), B1src, tn3);
    GBAR();
    __builtin_amdgcn_s_setprio(1); MMQ(af1, bf1, 4, 2); __builtin_amdgcn_s_setprio(0);
    WVM(6);
    GBAR();
  }
  asm volatile("s_waitcnt vmcnt(0)" ::: "memory");

  // ---- epilogue: v = up * silu(gate); acc[i][j] (j<2)=up, acc[i][j+2]=gate, same col ----
#pragma unroll
  for (int i = 0; i < 8; ++i) {
    const int row = m0 + (i >> 2) * 128 + wr * 64 + (i & 3) * 16 + s4 * 4;
#pragma unroll
    for (int j = 0; j < 2; ++j) {
      const int col = n0 + wc * 32 + j * 16 + frow;
#pragma unroll
      for (int r = 0; r < 4; ++r) {
        const float g = acc[i][j + 2][r];
        const float v = acc[i][j][r] * (g / (1.f + __expf(-g)));
        C[(size_t)(row + r) * 4096 + col] = f2b(v);
      }
    }
  }
}

// ---------------- Flash attention (causal), dh=64, S^T form ----------------
// Direct-from-L2 K/V fragment loads (no LDS staging, no barriers): K+V = 16 MB total,
// reread 16x per bh -> L2-resident. One 512-thread block = two balanced q-tiles
// (waves 0-3: qblk=2*qi, waves 4-7: qblk=15-2*qi) sharing the same (b,h) -> every CU
// keeps 8 waves resident for the whole kernel (uniform 17 kb-units per block).
__global__ __launch_bounds__(512, 2)
void attn_kernel(const unsigned short* __restrict__ qkv,  // [B*S, 2048] bf16: Q(scaled),K
                 const unsigned short* __restrict__ vt,   // [B*1024, 2048] bf16: V^T
                 unsigned short* __restrict__ out) {      // [B*S, 1024] bf16
  extern __shared__ __align__(16) unsigned int pl[];      // [8][64*36] uints = 72 KiB
  const int bh = blockIdx.x & 31;
  const int qi = blockIdx.x >> 5;                    // 0..7
  const int b = bh >> 4, h = bh & 15;
  const int tid = threadIdx.x;
  const int gw = tid >> 6;                           // 0..7 (wave in block)
  const int w = gw & 3;                              // wave within q-tile
  const int qblk = (gw < 4) ? (2 * qi) : (15 - 2 * qi);
  const int lane = tid & 63;
  const int f = lane & 15, g = lane >> 4;
  const int fk = g * 8, g4 = g * 4;

  const unsigned short* Qb = qkv + (size_t)(b * 2048) * 2048 + h * 64;
  const unsigned short* Kb = Qb + 1024;
  const unsigned short* Vt = vt + ((size_t)(b * 16 + h) * 64) * 2048;

  const int q0 = qblk * 128 + w * 32;
  short8 qf[2][2];
#pragma unroll
  for (int i = 0; i < 2; ++i)
#pragma unroll
    for (int kq = 0; kq < 2; ++kq)
      qf[i][kq] = *(const short8*)(Qb + (size_t)(q0 + 16*i + f) * 2048 + kq * 32 + fk);

  float m_s[2] = {-1e30f, -1e30f}, l_s[2] = {0.f, 0.f};
  floatx4 o[4][2];
#pragma unroll
  for (int mt = 0; mt < 4; ++mt)
#pragma unroll
    for (int i = 0; i < 2; ++i) o[mt][i] = (floatx4){0.f, 0.f, 0.f, 0.f};

  unsigned int* plw = pl + gw * (64 * 36);

  for (int kb = 0; kb <= qblk; ++kb) {
    const unsigned short* Kt = Kb + (size_t)(kb * 128) * 2048 + fk;
    const unsigned short* Vc = Vt + kb * 128 + fk;

    const bool diag = (kb == qblk);
    const int jhi0 = diag ? 2 * w : 7;
    const int jhi1 = diag ? 2 * w + 1 : 7;

    floatx4 s[8][2];
#pragma unroll
    for (int j = 0; j < 8; ++j) {
      if (j > jhi1) continue;
      const unsigned short* Kr = Kt + (size_t)(16*j + f) * 2048;
      short8 kf0 = *(const short8*)(Kr);
      short8 kf1 = *(const short8*)(Kr + 32);
      __builtin_amdgcn_s_setprio(1);
#pragma unroll
      for (int i = 0; i < 2; ++i) {
        if (j > (i ? jhi1 : jhi0)) continue;
        s[j][i] = (floatx4){0.f, 0.f, 0.f, 0.f};
        s[j][i] = __builtin_amdgcn_mfma_f32_16x16x32_bf16(kf0, qf[i][0], s[j][i], 0, 0, 0);
        s[j][i] = __builtin_amdgcn_mfma_f32_16x16x32_bf16(kf1, qf[i][1], s[j][i], 0, 0, 0);
      }
      __builtin_amdgcn_s_setprio(0);
    }
    if (diag) {
#pragma unroll
      for (int i = 0; i < 2; ++i) {
        const int qo = 32 * w + 16 * i + f;
        const int jh = i ? jhi1 : jhi0;
#pragma unroll
        for (int j = 0; j < 8; ++j) {
          if (j > jh) continue;
#pragma unroll
          for (int r = 0; r < 4; ++r)
            if (16 * j + g4 + r > qo) s[j][i][r] = -1e30f;
        }
      }
    }
#pragma unroll
    for (int i = 0; i < 2; ++i) {
      const int jh = i ? jhi1 : jhi0;
      float mx = -1e30f;
#pragma unroll
      for (int j = 0; j < 8; ++j) {
        if (j > jh) continue;
#pragma unroll
        for (int r = 0; r < 4; ++r) mx = fmaxf(mx, s[j][i][r]);
      }
      mx = fmaxf(mx, __shfl_xor(mx, 16));
      mx = fmaxf(mx, __shfl_xor(mx, 32));
      const float mnew = fmaxf(m_s[i], mx);
      const float alpha = exp2f(m_s[i] - mnew);
      float rs = 0.f;
#pragma unroll
      for (int j = 0; j < 8; ++j) {
        if (j > jh) continue;
#pragma unroll
        for (int r = 0; r < 4; ++r) {
          float pv = exp2f(s[j][i][r] - mnew);
          s[j][i][r] = pv;
          rs += pv;
        }
      }
      rs += __shfl_xor(rs, 16);
      rs += __shfl_xor(rs, 32);
      l_s[i] = l_s[i] * alpha + rs;
      m_s[i] = mnew;
#pragma unroll
      for (int mt = 0; mt < 4; ++mt) o[mt][i] *= alpha;
    }
#pragma unroll
    for (int i = 0; i < 2; ++i) {
      const int jh = i ? jhi1 : jhi0;
#pragma unroll
      for (int j = 0; j < 8; ++j) {
        if (j > jh) continue;
        plw[(8*j + 2*g + 0) * 36 + 16*i + f] = f2b2(s[j][i][0], s[j][i][1]);
        plw[(8*j + 2*g + 1) * 36 + 16*i + f] = f2b2(s[j][i][2], s[j][i][3]);
      }
    }
    if (diag) {
      plw[(8*(2*w + 1) + 2*g + 0) * 36 + f] = 0u;
      plw[(8*(2*w + 1) + 2*g + 1) * 36 + f] = 0u;
    }
    const int chi = diag ? w : 3;
#pragma unroll
    for (int c = 0; c < 4; ++c) {
      if (c > chi) continue;
      union { unsigned int d[4]; short8 v; } pb[2];
#pragma unroll
      for (int i = 0; i < 2; ++i)
#pragma unroll
        for (int k = 0; k < 4; ++k)
          pb[i].d[k] = plw[(16*c + 4*g + k) * 36 + 16*i + f];
#pragma unroll
      for (int mt = 0; mt < 4; ++mt) {
        short8 va = *(const short8*)(Vc + (size_t)(16*mt + f) * 2048 + c * 32);
        __builtin_amdgcn_s_setprio(1);
#pragma unroll
        for (int i = 0; i < 2; ++i)
          o[mt][i] = __builtin_amdgcn_mfma_f32_16x16x32_bf16(va, pb[i].v, o[mt][i], 0, 0, 0);
        __builtin_amdgcn_s_setprio(0);
      }
    }
  }

#pragma unroll
  for (int i = 0; i < 2; ++i) {
    const float inv = 1.0f / l_s[i];
    unsigned short* orow = out + (size_t)(b * 2048 + q0 + 16*i + f) * 1024 + h * 64;
#pragma unroll
    for (int mt = 0; mt < 4; ++mt) {
      ushort4 ov;
      ov.x = f2b(o[mt][i][0] * inv);
      ov.y = f2b(o[mt][i][1] * inv);
      ov.z = f2b(o[mt][i][2] * inv);
      ov.w = f2b(o[mt][i][3] * inv);
      *(ushort4*)(orow + 16 * mt + g4) = ov;
    }
  }
}

// ---------------- launcher ----------------
extern "C" void kernel_launch(void* const* d_in, const int* in_sizes, int n_in,
                              void* d_out, int out_size, void* d_ws, size_t ws_size,
                              hipStream_t stream) {
  const float* x      = (const float*)d_in[0];   // [2,2048,1024]
  const float* w_qkv  = (const float*)d_in[1];   // [3072,1024]
  const float* w_o    = (const float*)d_in[2];   // [1024,1024]
  const float* w_up   = (const float*)d_in[3];   // [4096,1024]
  const float* w_gate = (const float*)d_in[4];   // [4096,1024]
  const float* w_down = (const float*)d_in[5];   // [1024,4096]
  const float* scale1 = (const float*)d_in[6];
  const float* scale2 = (const float*)d_in[7];

  char* ws = (char*)d_ws;
  unsigned short* wq_b = (unsigned short*)(ws);                 //  6,291,456 B
  unsigned short* wo_b = (unsigned short*)(ws +  6291456);      //  2,097,152 B
  unsigned short* wu_b = (unsigned short*)(ws +  8388608);      //  8,388,608 B
  unsigned short* wg_b = (unsigned short*)(ws + 16777216);      //  8,388,608 B
  unsigned short* wd_b = (unsigned short*)(ws + 25165824);      //  8,388,608 B
  unsigned short* qkv  = (unsigned short*)(ws + 33554432);      // 16,777,216 B (Q,K; ldc 2048)
  unsigned short* hup  = (unsigned short*)(ws + 33554432);      // 33,554,432 B (aliases qkv+vT+attnb)
  unsigned short* vT   = (unsigned short*)(ws + 50331648);      //  8,388,608 B (V^T)
  unsigned short* attnb= (unsigned short*)(ws + 58720256);      //  8,388,608 B
  unsigned short* xn   = (unsigned short*)(ws + 67108864);      //  8,388,608 B
  float*          x1   = (float*)         (ws + 75497472);      // 16,777,216 B (fp32)
  float*          outp = (float*)d_out;                         // fp32

  // split-K partials (aliased over dead regions at their point of use):
  float* wo_p0   = (float*)(ws + 33554432);  // over qkv (dead after attn)
  float* wo_p1   = (float*)d_out;            // d_out unused until MLP end
  float* down_p0 = (float*)d_out;            // slice 0 -> d_out
  float* down_p1 = (float*)(ws + 8388608);   // over wu_b+wg_b (dead after upgate)

  const int M = 4096;
  dim3 blk(256);

  static int lds_opted = 0;
  if (!lds_opted) {
    hipFuncSetAttribute((const void*)gemm256_upgate,
                        hipFuncAttributeMaxDynamicSharedMemorySize, 131072);
    hipFuncSetAttribute((const void*)attn_kernel,
                        hipFuncAttributeMaxDynamicSharedMemorySize, 73728);
    lds_opted = 1;
  }

  // all weights fp32 -> bf16 in one dispatch (4,194,304 float4s)
  cvt_all_kernel<<<16384, blk, 0, stream>>>(w_qkv, w_o, w_up, w_gate, w_down,
                                            wq_b, wo_b, wu_b, wg_b, wd_b);

  // x1 = x + W_o( attn( rms(x) ) )    [W_o via split-K, reduce fused into rmsnorm_res2]
  rmsnorm_kernel<<<4096, blk, 0, stream>>>(x, scale1, xn);
  gemm_bt<EPI_QKV, unsigned short, unsigned short>
      <<<dim3(24, 32), blk, 0, stream>>>(xn, wq_b, qkv, (const unsigned short*)nullptr, vT,
                                         M, 3072, 1024, 2048);
  attn_kernel<<<dim3(256), dim3(512), 73728, stream>>>(qkv, vT, attnb);
  gemm_bt_splitk<<<dim3(8, 32, 2), blk, 0, stream>>>(attnb, wo_b, wo_p0, wo_p1,
                                                     M, 1024, 1024, 512);

  // x1 = x + p0 + p1 ; xn = rms(x1)
  rmsnorm_res2_kernel<<<4096, blk, 0, stream>>>(x, wo_p0, wo_p1, scale2, x1, xn);

  // out = x1 + W_down( up(rms) * silu(gate(rms)) )   [W_down via split-K]
  gemm256_upgate<<<dim3(512), dim3(512), 131072, stream>>>(xn, wu_b, wg_b, hup);
  gemm_bt_splitk<<<dim3(8, 32, 2), blk, 0, stream>>>(hup, wd_b, down_p0, down_p1,
                                                     M, 1024, 4096, 2048);
  reduce_out_kernel<<<4096, blk, 0, stream>>>(x1, down_p1, outp);

  (void)in_sizes; (void)n_in; (void)out_size; (void)ws_size;
}

// Round 4
// 403.200 us; speedup vs baseline: 1.1835x; 1.1835x over previous
//
#include <hip/hip_runtime.h>

// TransformerBlock: x = x + attn(rms(x)); x = x + mlp(rms(x))
// B=2, S=2048, D=1024, H=16, dh=64, EXP=4. Inputs/outputs fp32; internal bf16 MFMA.

typedef __attribute__((ext_vector_type(8))) short short8;   // 8 x bf16 = 4 VGPR
typedef __attribute__((ext_vector_type(4))) float floatx4;  // MFMA 16x16 acc

#define EPI_NONE 0
#define EPI_RES  1
#define EPI_GATE 2
#define EPI_QKV  3

#define QSCALE 0.1803368801f   // 0.125 * log2(e): folded into Q so softmax is base-2

__device__ __forceinline__ float b2f(unsigned short u) {
  union { unsigned int i; float f; } c; c.i = ((unsigned int)u) << 16; return c.f;
}
__device__ __forceinline__ unsigned short f2b(float f) {
  union { float f; unsigned int u; } c; c.f = f;
  unsigned int r = 0x7fffu + ((c.u >> 16) & 1u);
  return (unsigned short)((c.u + r) >> 16);
}
__device__ __forceinline__ unsigned int f2b2(float a, float b) {
  return (unsigned int)f2b(a) | ((unsigned int)f2b(b) << 16);
}

__device__ __forceinline__ void load_lds16(const void* g, void* l) {
  __builtin_amdgcn_global_load_lds(
      (const __attribute__((address_space(1))) unsigned int*)g,
      (__attribute__((address_space(3))) unsigned int*)l, 16, 0, 0);
}

#define GBAR() __builtin_amdgcn_s_barrier()
#define WLG()  asm volatile("s_waitcnt lgkmcnt(0)" ::: "memory")
#define WVM(N) asm volatile("s_waitcnt vmcnt(" #N ")" ::: "memory")

// ---------------- fused fp32 -> bf16 convert of all 5 weights ----------------
// float4 units: wq 786432, wo 262144, wu/wg/wd 1048576 each; total 4194304.
__global__ __launch_bounds__(256)
void cvt_all_kernel(const float* __restrict__ wq, const float* __restrict__ wo,
                    const float* __restrict__ wu, const float* __restrict__ wg,
                    const float* __restrict__ wd,
                    unsigned short* __restrict__ oq, unsigned short* __restrict__ oo,
                    unsigned short* __restrict__ ou, unsigned short* __restrict__ og,
                    unsigned short* __restrict__ od) {
  int i = blockIdx.x * 256 + threadIdx.x;
  const float* src; unsigned short* dst; int k;
  if (i < 786432)        { src = wq; dst = oq; k = i; }
  else if (i < 1048576)  { src = wo; dst = oo; k = i - 786432; }
  else if (i < 2097152)  { src = wu; dst = ou; k = i - 1048576; }
  else if (i < 3145728)  { src = wg; dst = og; k = i - 2097152; }
  else                   { src = wd; dst = od; k = i - 3145728; }
  float4 v = ((const float4*)src)[k];
  ushort4 o;
  o.x = f2b(v.x); o.y = f2b(v.y); o.z = f2b(v.z); o.w = f2b(v.w);
  ((ushort4*)dst)[k] = o;
}

// ---------------- RMSNorm: one block per row of 1024, fp32 in -> bf16 out ----------------
__global__ __launch_bounds__(256)
void rmsnorm_kernel(const float* __restrict__ x,
                    const float* __restrict__ scale,
                    unsigned short* __restrict__ y) {
  const int row = blockIdx.x;
  const int tid = threadIdx.x;
  const int base = row * 1024 + tid * 4;
  float4 v = *(const float4*)(x + base);
  float ss = v.x*v.x + v.y*v.y + v.z*v.z + v.w*v.w;
#pragma unroll
  for (int d = 32; d > 0; d >>= 1) ss += __shfl_down(ss, d);
  __shared__ float red[4];
  const int wave = tid >> 6, lane = tid & 63;
  if (lane == 0) red[wave] = ss;
  __syncthreads();
  float tot = red[0] + red[1] + red[2] + red[3];
  float rs = rsqrtf(tot * (1.0f/1024.0f) + 1e-6f);
  float4 sv = *(const float4*)(scale + tid * 4);
  ushort4 o;
  o.x = f2b(v.x * rs * sv.x);
  o.y = f2b(v.y * rs * sv.y);
  o.z = f2b(v.z * rs * sv.z);
  o.w = f2b(v.w * rs * sv.w);
  *(ushort4*)(y + base) = o;
}

// ---------------- RMSNorm + residual reduce: x1 = x + p0 + p1; y = rms(x1) ----------------
__global__ __launch_bounds__(256)
void rmsnorm_res2_kernel(const float* __restrict__ x,
                         const float* __restrict__ p0,
                         const float* __restrict__ p1,
                         const float* __restrict__ scale,
                         float* __restrict__ x1,
                         unsigned short* __restrict__ y) {
  const int row = blockIdx.x;
  const int tid = threadIdx.x;
  const int base = row * 1024 + tid * 4;
  float4 a = *(const float4*)(x + base);
  float4 b = *(const float4*)(p0 + base);
  float4 c = *(const float4*)(p1 + base);
  float4 v;
  v.x = a.x + b.x + c.x; v.y = a.y + b.y + c.y;
  v.z = a.z + b.z + c.z; v.w = a.w + b.w + c.w;
  *(float4*)(x1 + base) = v;
  float ss = v.x*v.x + v.y*v.y + v.z*v.z + v.w*v.w;
#pragma unroll
  for (int d = 32; d > 0; d >>= 1) ss += __shfl_down(ss, d);
  __shared__ float red[4];
  const int wave = tid >> 6, lane = tid & 63;
  if (lane == 0) red[wave] = ss;
  __syncthreads();
  float tot = red[0] + red[1] + red[2] + red[3];
  float rs = rsqrtf(tot * (1.0f/1024.0f) + 1e-6f);
  float4 sv = *(const float4*)(scale + tid * 4);
  ushort4 o;
  o.x = f2b(v.x * rs * sv.x);
  o.y = f2b(v.y * rs * sv.y);
  o.z = f2b(v.z * rs * sv.z);
  o.w = f2b(v.w * rs * sv.w);
  *(ushort4*)(y + base) = o;
}

// ---------------- final reduce: outp = x1 + outp + p1 (outp holds slice-0 partial) ----------------
__global__ __launch_bounds__(256)
void reduce_out_kernel(const float* __restrict__ x1,
                       const float* __restrict__ p1,
                       float* outp) {
  int i = blockIdx.x * 256 + threadIdx.x;
  float4 a = ((const float4*)x1)[i];
  float4 b = ((const float4*)p1)[i];
  float4 c = ((float4*)outp)[i];
  float4 v;
  v.x = a.x + b.x + c.x; v.y = a.y + b.y + c.y;
  v.z = a.z + b.z + c.z; v.w = a.w + b.w + c.w;
  ((float4*)outp)[i] = v;
}

// ---------------- GEMM: C[M,ldc] = A[M,K] @ B[N,K]^T (m97 structure) ----------------
// EPI_QKV: Q cols (<1024) scaled by QSCALE; V cols (>=2048) redirected to VT[b,h,d][s].
template<int EPI, typename OutT, typename ResT>
__global__ __launch_bounds__(256)
void gemm_bt(const unsigned short* __restrict__ A,
             const unsigned short* __restrict__ B,
             OutT* C, const ResT* R, unsigned short* VT,
             int M, int N, int K, int ldc) {
  __shared__ __align__(16) unsigned short As[128 * 32];
  __shared__ __align__(16) unsigned short Bs[128 * 32];
  const int tid = threadIdx.x;
  const int wave = tid >> 6;
  const int lane = tid & 63;
  const int m0 = blockIdx.y * 128;
  const int n0 = blockIdx.x * 128;
  const int wm = (wave & 1) * 64;
  const int wn = (wave >> 1) * 64;
  const int frow = lane & 15;
  const int fk = (lane >> 4) * 8;

  floatx4 acc[4][4];
#pragma unroll
  for (int i = 0; i < 4; ++i)
#pragma unroll
    for (int j = 0; j < 4; ++j) acc[i][j] = (floatx4){0.f, 0.f, 0.f, 0.f};

  const int srow = lane >> 2;
  const int scol = (lane & 3) * 8;
  const unsigned short* Ag  = A + (size_t)(m0 + wave * 16 + srow) * K + scol;
  const unsigned short* Ag2 = A + (size_t)(m0 + (wave + 4) * 16 + srow) * K + scol;
  const unsigned short* Bg  = B + (size_t)(n0 + wave * 16 + srow) * K + scol;
  const unsigned short* Bg2 = B + (size_t)(n0 + (wave + 4) * 16 + srow) * K + scol;

  for (int k0 = 0; k0 < K; k0 += 32) {
    __syncthreads();
    load_lds16(Ag + k0,  &As[wave * 512]);
    load_lds16(Ag2 + k0, &As[(wave + 4) * 512]);
    load_lds16(Bg + k0,  &Bs[wave * 512]);
    load_lds16(Bg2 + k0, &Bs[(wave + 4) * 512]);
    __syncthreads();
    short8 af[4], bf[4];
#pragma unroll
    for (int i = 0; i < 4; ++i) af[i] = *(const short8*)&As[(wm + 16*i + frow)*32 + fk];
#pragma unroll
    for (int j = 0; j < 4; ++j) bf[j] = *(const short8*)&Bs[(wn + 16*j + frow)*32 + fk];
#pragma unroll
    for (int i = 0; i < 4; ++i)
#pragma unroll
      for (int j = 0; j < 4; ++j)
        acc[i][j] = __builtin_amdgcn_mfma_f32_16x16x32_bf16(af[i], bf[j], acc[i][j], 0, 0, 0);
  }

  const int g4 = (lane >> 4) * 4;

  if constexpr (EPI == EPI_QKV) {
    if (n0 >= 2048) {
      // V tile: store transposed into VT[(b*16+h)*64+dd][s]
#pragma unroll
      for (int i = 0; i < 4; ++i) {
        const int row0 = m0 + wm + 16*i + g4;     // token index (r=0)
        const int b = row0 >> 11, s0 = row0 & 2047;
#pragma unroll
        for (int j = 0; j < 4; ++j) {
          const int col = n0 + wn + 16*j + frow;  // 2048..3071
          const int dg = col - 2048;
          const int rowv = (b << 10) + dg;        // (b*16+h)*64+dd == b*1024+dg
          ushort4 ov;
          ov.x = f2b(acc[i][j][0]);
          ov.y = f2b(acc[i][j][1]);
          ov.z = f2b(acc[i][j][2]);
          ov.w = f2b(acc[i][j][3]);
          *(ushort4*)(VT + (size_t)rowv * 2048 + s0) = ov;
        }
      }
      return;
    }
  }

  const float qs = (EPI == EPI_QKV && n0 < 1024) ? QSCALE : 1.0f;
#pragma unroll
  for (int i = 0; i < 4; ++i) {
#pragma unroll
    for (int r = 0; r < 4; ++r) {
      const int row = m0 + wm + 16*i + g4 + r;
#pragma unroll
      for (int j = 0; j < 4; ++j) {
        const int col = n0 + wn + 16*j + frow;
        const size_t idx = (size_t)row * ldc + col;
        float v = acc[i][j][r];
        if constexpr (EPI == EPI_RES) {
          v += (float)R[idx];
        } else if constexpr (EPI == EPI_GATE) {
          float up = b2f((unsigned short)R[idx]);
          v = up * (v / (1.f + __expf(-v)));
        } else if constexpr (EPI == EPI_QKV) {
          v *= qs;
        }
        if constexpr (sizeof(OutT) == 4) C[idx] = v;
        else                             C[idx] = f2b(v);
      }
    }
  }
}

// ---------------- Split-K GEMM: P_z[M,N] = A[M, z*Ks : (z+1)*Ks] @ B^T slice ----------------
__global__ __launch_bounds__(256)
void gemm_bt_splitk(const unsigned short* __restrict__ A,
                    const unsigned short* __restrict__ B,
                    float* __restrict__ P0, float* __restrict__ P1,
                    int M, int N, int K, int Ks) {
  __shared__ __align__(16) unsigned short As[128 * 32];
  __shared__ __align__(16) unsigned short Bs[128 * 32];
  const int tid = threadIdx.x;
  const int wave = tid >> 6;
  const int lane = tid & 63;
  const int m0 = blockIdx.y * 128;
  const int n0 = blockIdx.x * 128;
  const int z = blockIdx.z;
  float* C = z ? P1 : P0;
  const int kbase = z * Ks;
  const int wm = (wave & 1) * 64;
  const int wn = (wave >> 1) * 64;
  const int frow = lane & 15;
  const int fk = (lane >> 4) * 8;

  floatx4 acc[4][4];
#pragma unroll
  for (int i = 0; i < 4; ++i)
#pragma unroll
    for (int j = 0; j < 4; ++j) acc[i][j] = (floatx4){0.f, 0.f, 0.f, 0.f};

  const int srow = lane >> 2;
  const int scol = (lane & 3) * 8;
  const unsigned short* Ag  = A + (size_t)(m0 + wave * 16 + srow) * K + kbase + scol;
  const unsigned short* Ag2 = A + (size_t)(m0 + (wave + 4) * 16 + srow) * K + kbase + scol;
  const unsigned short* Bg  = B + (size_t)(n0 + wave * 16 + srow) * K + kbase + scol;
  const unsigned short* Bg2 = B + (size_t)(n0 + (wave + 4) * 16 + srow) * K + kbase + scol;

  for (int k0 = 0; k0 < Ks; k0 += 32) {
    __syncthreads();
    load_lds16(Ag + k0,  &As[wave * 512]);
    load_lds16(Ag2 + k0, &As[(wave + 4) * 512]);
    load_lds16(Bg + k0,  &Bs[wave * 512]);
    load_lds16(Bg2 + k0, &Bs[(wave + 4) * 512]);
    __syncthreads();
    short8 af[4], bf[4];
#pragma unroll
    for (int i = 0; i < 4; ++i) af[i] = *(const short8*)&As[(wm + 16*i + frow)*32 + fk];
#pragma unroll
    for (int j = 0; j < 4; ++j) bf[j] = *(const short8*)&Bs[(wn + 16*j + frow)*32 + fk];
#pragma unroll
    for (int i = 0; i < 4; ++i)
#pragma unroll
      for (int j = 0; j < 4; ++j)
        acc[i][j] = __builtin_amdgcn_mfma_f32_16x16x32_bf16(af[i], bf[j], acc[i][j], 0, 0, 0);
  }

  const int g4 = (lane >> 4) * 4;
#pragma unroll
  for (int i = 0; i < 4; ++i)
#pragma unroll
    for (int r = 0; r < 4; ++r) {
      const int row = m0 + wm + 16*i + g4 + r;
#pragma unroll
      for (int j = 0; j < 4; ++j) {
        const int col = n0 + wn + 16*j + frow;
        C[(size_t)row * N + col] = acc[i][j][r];
      }
    }
}

// ================= 256x(128out) 8-phase up+gate GEMM (m201 template, T1+T2+T3+T4+T5) =======
// A [4096,1024] bf16, Bu/Bg [4096,1024] bf16; C[row*4096+col] = up * silu(gate), bf16.
// BM=256, BK=64, 8 waves (2M x 4N), per-wave 128 rows x 32 up-cols (+32 gate).
// LDS 128 KiB: A[q][h] at (q*2+h)*8192 ushorts, B[q][h] at 32768 + (q*2+h)*8192.
//   B-half0 = w_up rows [bx*128,+128), B-half1 = w_gate rows (same out cols!).
// Swizzle: LDS(row, g) holds global granule g^(row&7); read XOR matches (both-sides).
// Stage slots: ph1:(t+1).A1  ph2-5:(t+2).{A0,B0,B1,A1}  ph6-8:(t+3).{A0,B0,B1}.
// vmcnt(6) (=3 half-tiles in flight) only at ph4/ph8, before the closing barrier.

#define A_OFF(q,h) (((q)*2+(h))*8192)
#define B_OFF(q,h) (32768 + ((q)*2+(h))*8192)

#define STAGE(LB, SRC, T) do {                                               \
    const unsigned short* _s = (SRC) + (size_t)r0 * 1024 + (T) * 64 + gs;    \
    load_lds16(_s,             &lds[(LB) + wave * 512]);                     \
    load_lds16(_s + 64 * 1024, &lds[(LB) + 4096 + wave * 512]);              \
  } while (0)

#define LDA4(dst, q, h) do {                                                 \
    const unsigned short* _b = &lds[A_OFF(q,h) + arow];                      \
    _Pragma("unroll")                                                        \
    for (int _i = 0; _i < 4; ++_i) {                                         \
      dst[_i][0] = *(const short8*)(_b + _i * 1024 + g0);                    \
      dst[_i][1] = *(const short8*)(_b + _i * 1024 + g1);                    \
    }                                                                        \
  } while (0)

#define LDB2(dst, q, h) do {                                                 \
    const unsigned short* _b = &lds[B_OFF(q,h) + brow];                      \
    _Pragma("unroll")                                                        \
    for (int _j = 0; _j < 2; ++_j) {                                         \
      dst[_j][0] = *(const short8*)(_b + _j * 1024 + g0);                    \
      dst[_j][1] = *(const short8*)(_b + _j * 1024 + g1);                    \
    }                                                                        \
  } while (0)

#define MMQ(aa, bb, IO, JO) do {                                             \
    _Pragma("unroll")                                                        \
    for (int _i = 0; _i < 4; ++_i)                                           \
      _Pragma("unroll")                                                      \
      for (int _j = 0; _j < 2; ++_j) {                                       \
        acc[(IO)+_i][(JO)+_j] = __builtin_amdgcn_mfma_f32_16x16x32_bf16(     \
            aa[_i][0], bb[_j][0], acc[(IO)+_i][(JO)+_j], 0, 0, 0);           \
        acc[(IO)+_i][(JO)+_j] = __builtin_amdgcn_mfma_f32_16x16x32_bf16(     \
            aa[_i][1], bb[_j][1], acc[(IO)+_i][(JO)+_j], 0, 0, 0);           \
      }                                                                      \
  } while (0)

__global__ __launch_bounds__(512, 2)
void gemm256_upgate(const unsigned short* __restrict__ A,
                    const unsigned short* __restrict__ Bu,
                    const unsigned short* __restrict__ Bg,
                    unsigned short* __restrict__ C) {
  extern __shared__ __align__(16) unsigned short lds[];   // 65536 ushorts = 128 KiB
  const int tid  = threadIdx.x;
  const int wave = tid >> 6;
  const int lane = tid & 63;
  const int wr   = wave >> 2;       // 0..1  M-split
  const int wc   = wave & 3;        // 0..3  N-split
  const int frow = lane & 15;
  const int s4   = lane >> 4;       // 0..3

  // bijective XCD swizzle (512 % 8 == 0)
  const int orig = blockIdx.x;
  const int swz  = (orig & 7) * 64 + (orig >> 3);
  const int bx   = swz & 31;        // n-tile (out cols /128)
  const int by   = swz >> 5;        // m-tile (rows /256)
  const int m0   = by * 256;
  const int n0   = bx * 128;

  // fragment-read swizzled granule offsets (ushorts)
  const int f7 = frow & 7;
  const int g0 = ((0 + s4) ^ f7) * 8;    // kk=0
  const int g1 = ((4 + s4) ^ f7) * 8;    // kk=1
  const int arow = (wr * 64 + frow) * 64;   // + (i&3)*1024
  const int brow = (wc * 32 + frow) * 64;   // + (j&1)*1024

  // staging per-lane: LDS row r0 (+64 for round 1), pre-swizzled source granule
  const int r0 = wave * 8 + (lane >> 3);
  const int gs = ((lane & 7) ^ (lane >> 3)) * 8;

  const unsigned short* Asrc  = A  + (size_t)m0 * 1024;          // A-half1: +128*1024
  const unsigned short* B0src = Bu + (size_t)(bx * 128) * 1024;  // up rows
  const unsigned short* B1src = Bg + (size_t)(bx * 128) * 1024;  // gate rows (same cols)

  floatx4 acc[8][4];
#pragma unroll
  for (int i = 0; i < 8; ++i)
#pragma unroll
    for (int j = 0; j < 4; ++j) acc[i][j] = (floatx4){0.f, 0.f, 0.f, 0.f};

  // ---- prologue: tile0 {A0,B0,B1,A1}, vmcnt(4); tile1 {A0,B0,B1}, vmcnt(6) ----
  STAGE(A_OFF(0,0), Asrc, 0);
  STAGE(B_OFF(0,0), B0src, 0);
  STAGE(B_OFF(0,1), B1src, 0);
  STAGE(A_OFF(0,1), Asrc + 128 * 1024, 0);
  WVM(4);
  STAGE(A_OFF(1,0), Asrc, 1);
  STAGE(B_OFF(1,0), B0src, 1);
  STAGE(B_OFF(1,1), B1src, 1);
  WVM(6);
  GBAR();

  short8 af0[4][2], af1[4][2], bf0[2][2], bf1[2][2];

  for (int it = 0; it < 8; ++it) {
    const int t   = it * 2;                 // even tile -> buf0, odd -> buf1
    const int tn2 = (t + 2) & 15;           // wrapped (last iter stages are dead writes)
    const int tn3 = (t + 3) & 15;
    // ph1: (m0,n0) from buf0 | stage (t+1).A1
    LDA4(af0, 0, 0);
    LDB2(bf0, 0, 0);
    STAGE(A_OFF(1,1), Asrc + 128 * 1024, (t + 1) & 15);
    GBAR(); WLG();
    __builtin_amdgcn_s_setprio(1); MMQ(af0, bf0, 0, 0); __builtin_amdgcn_s_setprio(0);
    GBAR();
    // ph2: (m0,n1) | stage (t+2).A0
    LDB2(bf1, 0, 1);
    STAGE(A_OFF(0,0), Asrc, tn2);
    GBAR(); WLG();
    __builtin_amdgcn_s_setprio(1); MMQ(af0, bf1, 0, 2); __builtin_amdgcn_s_setprio(0);
    GBAR();
    // ph3: (m1,n0) | stage (t+2).B0
    LDA4(af1, 0, 1);
    STAGE(B_OFF(0,0), B0src, tn2);
    GBAR(); WLG();
    __builtin_amdgcn_s_setprio(1); MMQ(af1, bf0, 4, 0); __builtin_amdgcn_s_setprio(0);
    GBAR();
    // ph4: (m1,n1) | stage (t+2).B1 | vmcnt(6)
    STAGE(B_OFF(0,1), B1src, tn2);
    GBAR();
    __builtin_amdgcn_s_setprio(1); MMQ(af1, bf1, 4, 2); __builtin_amdgcn_s_setprio(0);
    WVM(6);
    GBAR();
    // ph5: (m0,n0) from buf1 | stage (t+2).A1
    LDA4(af0, 1, 0);
    LDB2(bf0, 1, 0);
    STAGE(A_OFF(0,1), Asrc + 128 * 1024, tn2);
    GBAR(); WLG();
    __builtin_amdgcn_s_setprio(1); MMQ(af0, bf0, 0, 0); __builtin_amdgcn_s_setprio(0);
    GBAR();
    // ph6: (m0,n1) | stage (t+3).A0
    LDB2(bf1, 1, 1);
    STAGE(A_OFF(1,0), Asrc, tn3);
    GBAR(); WLG();
    __builtin_amdgcn_s_setprio(1); MMQ(af0, bf1, 0, 2); __builtin_amdgcn_s_setprio(0);
    GBAR();
    // ph7: (m1,n0) | stage (t+3).B0
    LDA4(af1, 1, 1);
    STAGE(B_OFF(1,0), B0src, tn3);
    GBAR(); WLG();
    __builtin_amdgcn_s_setprio(1); MMQ(af1, bf0, 4, 0); __builtin_amdgcn_s_setprio(0);
    GBAR();
    // ph8: (m1,n1) | stage (t+3).B1 | vmcnt(6)
    STAGE(B_OFF(1,1), B1src, tn3);
    GBAR();
    __builtin_amdgcn_s_setprio(1); MMQ(af1, bf1, 4, 2); __builtin_amdgcn_s_setprio(0);
    WVM(6);
    GBAR();
  }
  asm volatile("s_waitcnt vmcnt(0)" ::: "memory");

  // ---- epilogue: v = up * silu(gate); acc[i][j] (j<2)=up, acc[i][j+2]=gate, same col ----
#pragma unroll
  for (int i = 0; i < 8; ++i) {
    const int row = m0 + (i >> 2) * 128 + wr * 64 + (i & 3) * 16 + s4 * 4;
#pragma unroll
    for (int j = 0; j < 2; ++j) {
      const int col = n0 + wc * 32 + j * 16 + frow;
#pragma unroll
      for (int r = 0; r < 4; ++r) {
        const float g = acc[i][j + 2][r];
        const float v = acc[i][j][r] * (g / (1.f + __expf(-g)));
        C[(size_t)(row + r) * 4096 + col] = f2b(v);
      }
    }
  }
}

// ---------------- Flash attention (causal), dh=64, S^T form ----------------
// Round-1 staged structure + (a) double-buffered K/V staging with raw s_barrier +
// counted vmcnt(8) (no per-iteration full drain), (b) LDS XOR-swizzle on Ks/Vs
// (pre-swizzled global source for global_load_lds, swizzled read), (c) in-register
// P^T via cvt_pk + v_permlane{32,16}_swap_b32 (pl LDS buffer eliminated).
__global__ __launch_bounds__(256, 2)
void attn_kernel(const unsigned short* __restrict__ qkv,  // [B*S, 2048] bf16: Q(scaled),K
                 const unsigned short* __restrict__ vt,   // [B*1024, 2048] bf16: V^T
                 unsigned short* __restrict__ out) {      // [B*S, 1024] bf16
  __shared__ __align__(16) unsigned short Ks[2][2][128 * 32];  // [buf][kq][key][32]: 32 KB
  __shared__ __align__(16) unsigned short Vs[2][4][64 * 32];   // [buf][c][d][32]:    32 KB
  const int lin = blockIdx.x;
  const int bh = lin & 31;
  const int q_idx = lin >> 5;                        // 0..15
  const int qblk = (q_idx < 8) ? (2 * q_idx) : (31 - 2 * q_idx);
  const int b = bh >> 4, h = bh & 15;
  const int tid = threadIdx.x, w = tid >> 6, lane = tid & 63;
  const int f = lane & 15, g = lane >> 4;
  const int fk = g * 8, g4 = g * 4;
  // swizzled LDS read granule: col = g ^ ((row%16)>>1 & 3); row%16 == f for all reads
  const int fks = (g ^ ((f >> 1) & 3)) * 8;

  const unsigned short* Qb = qkv + (size_t)(b * 2048) * 2048 + h * 64;
  const unsigned short* Kb = Qb + 1024;
  const unsigned short* Vt = vt + ((size_t)(b * 16 + h) * 64) * 2048;

  const int q0 = qblk * 128 + w * 32;
  short8 qf[2][2];
#pragma unroll
  for (int i = 0; i < 2; ++i)
#pragma unroll
    for (int kq = 0; kq < 2; ++kq)
      qf[i][kq] = *(const short8*)(Qb + (size_t)(q0 + 16*i + f) * 2048 + kq * 32 + fk);

  float m_s[2] = {-1e30f, -1e30f}, l_s[2] = {0.f, 0.f};
  floatx4 o[4][2];
#pragma unroll
  for (int mt = 0; mt < 4; ++mt)
#pragma unroll
    for (int i = 0; i < 2; ++i) o[mt][i] = (floatx4){0.f, 0.f, 0.f, 0.f};

  const int srow = lane >> 2;
  // pre-swizzled source granule: global granule (lane&3) ^ ((srow>>1)&3)
  const int scolx = ((lane & 3) ^ ((lane >> 3) & 3)) * 8;

  // per-wave stage: 8 x global_load_lds(16B) -> counted by WVM(8)
  auto stage = [&](int bb, int kb) {
#pragma unroll
    for (int u = 0; u < 2; ++u) {
      const int seg = w + 4 * u;
#pragma unroll
      for (int kq = 0; kq < 2; ++kq)
        load_lds16(Kb + (size_t)(kb * 128 + seg * 16 + srow) * 2048 + kq * 32 + scolx,
                   &Ks[bb][kq][seg * 512]);
    }
#pragma unroll
    for (int c = 0; c < 4; ++c)
      load_lds16(Vt + (size_t)(w * 16 + srow) * 2048 + kb * 128 + c * 32 + scolx,
                 &Vs[bb][c][w * 512]);
  };

  stage(0, 0);

  for (int kb = 0; kb <= qblk; ++kb) {
    const int cur = kb & 1;
    GBAR();                                   // all waves done reading buf[cur^1]
    if (kb < qblk) {
      stage(cur ^ 1, kb + 1);                 // prefetch next tile (in flight across compute)
      WVM(8);                                 // own buf[cur] loads (older 8) retired
    } else {
      WVM(0);
    }
    GBAR();                                   // buf[cur] complete for all waves
    __builtin_amdgcn_sched_barrier(0);

    const bool diag = (kb == qblk);
    const int jhi0 = diag ? 2 * w : 7;
    const int jhi1 = diag ? 2 * w + 1 : 7;

    floatx4 s[8][2];
#pragma unroll
    for (int j = 0; j < 8; ++j) {
      if (j > jhi1) continue;
      short8 kf0 = *(const short8*)&Ks[cur][0][(16*j + f) * 32 + fks];
      short8 kf1 = *(const short8*)&Ks[cur][1][(16*j + f) * 32 + fks];
      __builtin_amdgcn_s_setprio(1);
#pragma unroll
      for (int i = 0; i < 2; ++i) {
        if (j > (i ? jhi1 : jhi0)) continue;
        s[j][i] = (floatx4){0.f, 0.f, 0.f, 0.f};
        s[j][i] = __builtin_amdgcn_mfma_f32_16x16x32_bf16(kf0, qf[i][0], s[j][i], 0, 0, 0);
        s[j][i] = __builtin_amdgcn_mfma_f32_16x16x32_bf16(kf1, qf[i][1], s[j][i], 0, 0, 0);
      }
      __builtin_amdgcn_s_setprio(0);
    }
    if (diag) {
#pragma unroll
      for (int i = 0; i < 2; ++i) {
        const int qo = 32 * w + 16 * i + f;
        const int jh = i ? jhi1 : jhi0;
#pragma unroll
        for (int j = 0; j < 8; ++j) {
          if (j > jh) continue;
#pragma unroll
          for (int r = 0; r < 4; ++r)
            if (16 * j + g4 + r > qo) s[j][i][r] = -1e30f;
        }
      }
    }
#pragma unroll
    for (int i = 0; i < 2; ++i) {
      const int jh = i ? jhi1 : jhi0;
      float mx = -1e30f;
#pragma unroll
      for (int j = 0; j < 8; ++j) {
        if (j > jh) continue;
#pragma unroll
        for (int r = 0; r < 4; ++r) mx = fmaxf(mx, s[j][i][r]);
      }
      mx = fmaxf(mx, __shfl_xor(mx, 16));
      mx = fmaxf(mx, __shfl_xor(mx, 32));
      const float mnew = fmaxf(m_s[i], mx);
      const float alpha = exp2f(m_s[i] - mnew);
      float rs = 0.f;
#pragma unroll
      for (int j = 0; j < 8; ++j) {
        if (j > jh) continue;
#pragma unroll
        for (int r = 0; r < 4; ++r) {
          float pv = exp2f(s[j][i][r] - mnew);
          s[j][i][r] = pv;
          rs += pv;
        }
      }
      rs += __shfl_xor(rs, 16);
      rs += __shfl_xor(rs, 32);
      l_s[i] = l_s[i] * alpha + rs;
      m_s[i] = mnew;
#pragma unroll
      for (int mt = 0; mt < 4; ++mt) o[mt][i] *= alpha;
    }

    // PV: P^T B-fragments built in-register.
    // Source lane (f,g') holds S^T[k=16j+4g'+r][q=16i+f] in s[j][i][r].
    // Target lane (f,g) needs k = 32c+8g+m (m=0..7) as 4 uints (bf16 pairs).
    // With P=pair-pack of j=2c, Q=of j=2c+1:
    //   swap32(P,Q): P=[P.lo,Q.lo], Q=[P.hi,Q.hi]; then swap16(P,Q):
    //   P=[P.q0,P.q2,Q.q0,Q.q2]=d[0|1], Q=[P.q1,P.q3,Q.q1,Q.q3]=d[2|3].
    const int chi = diag ? w : 3;
#pragma unroll
    for (int c = 0; c < 4; ++c) {
      if (c > chi) continue;
      short8 pb[2];
#pragma unroll
      for (int i = 0; i < 2; ++i) {
        const int jh = i ? jhi1 : jhi0;
        unsigned int P01 = f2b2(s[2*c][i][0], s[2*c][i][1]);
        unsigned int P23 = f2b2(s[2*c][i][2], s[2*c][i][3]);
        unsigned int Q01 = 0u, Q23 = 0u;
        if (2*c + 1 <= jh) {                      // wave-uniform
          Q01 = f2b2(s[2*c+1][i][0], s[2*c+1][i][1]);
          Q23 = f2b2(s[2*c+1][i][2], s[2*c+1][i][3]);
        }
        asm("v_permlane32_swap_b32 %0, %1" : "+v"(P01), "+v"(Q01));
        asm("v_permlane32_swap_b32 %0, %1" : "+v"(P23), "+v"(Q23));
        asm("v_permlane16_swap_b32 %0, %1" : "+v"(P01), "+v"(Q01));
        asm("v_permlane16_swap_b32 %0, %1" : "+v"(P23), "+v"(Q23));
        union { unsigned int d[4]; short8 v; } pbu;
        pbu.d[0] = P01; pbu.d[1] = P23; pbu.d[2] = Q01; pbu.d[3] = Q23;
        pb[i] = pbu.v;
      }
#pragma unroll
      for (int mt = 0; mt < 4; ++mt) {
        short8 va = *(const short8*)&Vs[cur][c][(16*mt + f) * 32 + fks];
        __builtin_amdgcn_s_setprio(1);
#pragma unroll
        for (int i = 0; i < 2; ++i)
          o[mt][i] = __builtin_amdgcn_mfma_f32_16x16x32_bf16(va, pb[i], o[mt][i], 0, 0, 0);
        __builtin_amdgcn_s_setprio(0);
      }
    }
  }

#pragma unroll
  for (int i = 0; i < 2; ++i) {
    const float inv = 1.0f / l_s[i];
    unsigned short* orow = out + (size_t)(b * 2048 + q0 + 16*i + f) * 1024 + h * 64;
#pragma unroll
    for (int mt = 0; mt < 4; ++mt) {
      ushort4 ov;
      ov.x = f2b(o[mt][i][0] * inv);
      ov.y = f2b(o[mt][i][1] * inv);
      ov.z = f2b(o[mt][i][2] * inv);
      ov.w = f2b(o[mt][i][3] * inv);
      *(ushort4*)(orow + 16 * mt + g4) = ov;
    }
  }
}

// ---------------- launcher ----------------
extern "C" void kernel_launch(void* const* d_in, const int* in_sizes, int n_in,
                              void* d_out, int out_size, void* d_ws, size_t ws_size,
                              hipStream_t stream) {
  const float* x      = (const float*)d_in[0];   // [2,2048,1024]
  const float* w_qkv  = (const float*)d_in[1];   // [3072,1024]
  const float* w_o    = (const float*)d_in[2];   // [1024,1024]
  const float* w_up   = (const float*)d_in[3];   // [4096,1024]
  const float* w_gate = (const float*)d_in[4];   // [4096,1024]
  const float* w_down = (const float*)d_in[5];   // [1024,4096]
  const float* scale1 = (const float*)d_in[6];
  const float* scale2 = (const float*)d_in[7];

  char* ws = (char*)d_ws;
  unsigned short* wq_b = (unsigned short*)(ws);                 //  6,291,456 B
  unsigned short* wo_b = (unsigned short*)(ws +  6291456);      //  2,097,152 B
  unsigned short* wu_b = (unsigned short*)(ws +  8388608);      //  8,388,608 B
  unsigned short* wg_b = (unsigned short*)(ws + 16777216);      //  8,388,608 B
  unsigned short* wd_b = (unsigned short*)(ws + 25165824);      //  8,388,608 B
  unsigned short* qkv  = (unsigned short*)(ws + 33554432);      // 16,777,216 B (Q,K; ldc 2048)
  unsigned short* hup  = (unsigned short*)(ws + 33554432);      // 33,554,432 B (aliases qkv+vT+attnb)
  unsigned short* vT   = (unsigned short*)(ws + 50331648);      //  8,388,608 B (V^T)
  unsigned short* attnb= (unsigned short*)(ws + 58720256);      //  8,388,608 B
  unsigned short* xn   = (unsigned short*)(ws + 67108864);      //  8,388,608 B
  float*          x1   = (float*)         (ws + 75497472);      // 16,777,216 B (fp32)
  float*          outp = (float*)d_out;                         // fp32

  // split-K partials (aliased over dead regions at their point of use):
  float* wo_p0   = (float*)(ws + 33554432);  // over qkv (dead after attn)
  float* wo_p1   = (float*)d_out;            // d_out unused until MLP end
  float* down_p0 = (float*)d_out;            // slice 0 -> d_out
  float* down_p1 = (float*)(ws + 8388608);   // over wu_b+wg_b (dead after upgate)

  const int M = 4096;
  dim3 blk(256);

  static int lds_opted = 0;
  if (!lds_opted) {
    (void)hipFuncSetAttribute((const void*)gemm256_upgate,
                              hipFuncAttributeMaxDynamicSharedMemorySize, 131072);
    lds_opted = 1;
  }

  // all weights fp32 -> bf16 in one dispatch (4,194,304 float4s)
  cvt_all_kernel<<<16384, blk, 0, stream>>>(w_qkv, w_o, w_up, w_gate, w_down,
                                            wq_b, wo_b, wu_b, wg_b, wd_b);

  // x1 = x + W_o( attn( rms(x) ) )    [W_o via split-K, reduce fused into rmsnorm_res2]
  rmsnorm_kernel<<<4096, blk, 0, stream>>>(x, scale1, xn);
  gemm_bt<EPI_QKV, unsigned short, unsigned short>
      <<<dim3(24, 32), blk, 0, stream>>>(xn, wq_b, qkv, (const unsigned short*)nullptr, vT,
                                         M, 3072, 1024, 2048);
  attn_kernel<<<dim3(512), blk, 0, stream>>>(qkv, vT, attnb);
  gemm_bt_splitk<<<dim3(8, 32, 2), blk, 0, stream>>>(attnb, wo_b, wo_p0, wo_p1,
                                                     M, 1024, 1024, 512);

  // x1 = x + p0 + p1 ; xn = rms(x1)
  rmsnorm_res2_kernel<<<4096, blk, 0, stream>>>(x, wo_p0, wo_p1, scale2, x1, xn);

  // out = x1 + W_down( up(rms) * silu(gate(rms)) )   [W_down via split-K]
  gemm256_upgate<<<dim3(512), dim3(512), 131072, stream>>>(xn, wu_b, wg_b, hup);
  gemm_bt_splitk<<<dim3(8, 32, 2), blk, 0, stream>>>(hup, wd_b, down_p0, down_p1,
                                                     M, 1024, 4096, 2048);
  reduce_out_kernel<<<4096, blk, 0, stream>>>(x1, down_p1, outp);

  (void)in_sizes; (void)n_in; (void)out_size; (void)ws_size;
}

// Round 6
// 384.485 us; speedup vs baseline: 1.2412x; 1.0487x over previous
//
#include <hip/hip_runtime.h>

// TransformerBlock: x = x + attn(rms(x)); x = x + mlp(rms(x))
// B=2, S=2048, D=1024, H=16, dh=64, EXP=4. Inputs/outputs fp32; internal bf16 MFMA.

typedef __attribute__((ext_vector_type(8))) short short8;   // 8 x bf16 = 4 VGPR
typedef __attribute__((ext_vector_type(4))) float floatx4;  // MFMA 16x16 acc

#define EPI_NONE 0
#define EPI_RES  1
#define EPI_GATE 2
#define EPI_QKV  3

#define QSCALE 0.1803368801f   // 0.125 * log2(e): folded into Q so softmax is base-2

__device__ __forceinline__ float b2f(unsigned short u) {
  union { unsigned int i; float f; } c; c.i = ((unsigned int)u) << 16; return c.f;
}
__device__ __forceinline__ unsigned short f2b(float f) {
  union { float f; unsigned int u; } c; c.f = f;
  unsigned int r = 0x7fffu + ((c.u >> 16) & 1u);
  return (unsigned short)((c.u + r) >> 16);
}
__device__ __forceinline__ unsigned int f2b2(float a, float b) {
  return (unsigned int)f2b(a) | ((unsigned int)f2b(b) << 16);
}

__device__ __forceinline__ void load_lds16(const void* g, void* l) {
  __builtin_amdgcn_global_load_lds(
      (const __attribute__((address_space(1))) unsigned int*)g,
      (__attribute__((address_space(3))) unsigned int*)l, 16, 0, 0);
}

#define GBAR() __builtin_amdgcn_s_barrier()
#define WLG()  asm volatile("s_waitcnt lgkmcnt(0)" ::: "memory")
#define WVM(N) asm volatile("s_waitcnt vmcnt(" #N ")" ::: "memory")

// ---------------- fused fp32 -> bf16 convert of all 5 weights ----------------
// float4 units: wq 786432, wo 262144, wu/wg/wd 1048576 each; total 4194304.
__global__ __launch_bounds__(256)
void cvt_all_kernel(const float* __restrict__ wq, const float* __restrict__ wo,
                    const float* __restrict__ wu, const float* __restrict__ wg,
                    const float* __restrict__ wd,
                    unsigned short* __restrict__ oq, unsigned short* __restrict__ oo,
                    unsigned short* __restrict__ ou, unsigned short* __restrict__ og,
                    unsigned short* __restrict__ od) {
  int i = blockIdx.x * 256 + threadIdx.x;
  const float* src; unsigned short* dst; int k;
  if (i < 786432)        { src = wq; dst = oq; k = i; }
  else if (i < 1048576)  { src = wo; dst = oo; k = i - 786432; }
  else if (i < 2097152)  { src = wu; dst = ou; k = i - 1048576; }
  else if (i < 3145728)  { src = wg; dst = og; k = i - 2097152; }
  else                   { src = wd; dst = od; k = i - 3145728; }
  float4 v = ((const float4*)src)[k];
  ushort4 o;
  o.x = f2b(v.x); o.y = f2b(v.y); o.z = f2b(v.z); o.w = f2b(v.w);
  ((ushort4*)dst)[k] = o;
}

// ---------------- RMSNorm: one block per row of 1024, fp32 in -> bf16 out ----------------
__global__ __launch_bounds__(256)
void rmsnorm_kernel(const float* __restrict__ x,
                    const float* __restrict__ scale,
                    unsigned short* __restrict__ y) {
  const int row = blockIdx.x;
  const int tid = threadIdx.x;
  const int base = row * 1024 + tid * 4;
  float4 v = *(const float4*)(x + base);
  float ss = v.x*v.x + v.y*v.y + v.z*v.z + v.w*v.w;
#pragma unroll
  for (int d = 32; d > 0; d >>= 1) ss += __shfl_down(ss, d);
  __shared__ float red[4];
  const int wave = tid >> 6, lane = tid & 63;
  if (lane == 0) red[wave] = ss;
  __syncthreads();
  float tot = red[0] + red[1] + red[2] + red[3];
  float rs = rsqrtf(tot * (1.0f/1024.0f) + 1e-6f);
  float4 sv = *(const float4*)(scale + tid * 4);
  ushort4 o;
  o.x = f2b(v.x * rs * sv.x);
  o.y = f2b(v.y * rs * sv.y);
  o.z = f2b(v.z * rs * sv.z);
  o.w = f2b(v.w * rs * sv.w);
  *(ushort4*)(y + base) = o;
}

// ---------------- RMSNorm + residual reduce: x1 = x + p0 + p1; y = rms(x1) ----------------
__global__ __launch_bounds__(256)
void rmsnorm_res2_kernel(const float* __restrict__ x,
                         const float* __restrict__ p0,
                         const float* __restrict__ p1,
                         const float* __restrict__ scale,
                         float* __restrict__ x1,
                         unsigned short* __restrict__ y) {
  const int row = blockIdx.x;
  const int tid = threadIdx.x;
  const int base = row * 1024 + tid * 4;
  float4 a = *(const float4*)(x + base);
  float4 b = *(const float4*)(p0 + base);
  float4 c = *(const float4*)(p1 + base);
  float4 v;
  v.x = a.x + b.x + c.x; v.y = a.y + b.y + c.y;
  v.z = a.z + b.z + c.z; v.w = a.w + b.w + c.w;
  *(float4*)(x1 + base) = v;
  float ss = v.x*v.x + v.y*v.y + v.z*v.z + v.w*v.w;
#pragma unroll
  for (int d = 32; d > 0; d >>= 1) ss += __shfl_down(ss, d);
  __shared__ float red[4];
  const int wave = tid >> 6, lane = tid & 63;
  if (lane == 0) red[wave] = ss;
  __syncthreads();
  float tot = red[0] + red[1] + red[2] + red[3];
  float rs = rsqrtf(tot * (1.0f/1024.0f) + 1e-6f);
  float4 sv = *(const float4*)(scale + tid * 4);
  ushort4 o;
  o.x = f2b(v.x * rs * sv.x);
  o.y = f2b(v.y * rs * sv.y);
  o.z = f2b(v.z * rs * sv.z);
  o.w = f2b(v.w * rs * sv.w);
  *(ushort4*)(y + base) = o;
}

// ---------------- final reduce: outp = x1 + outp + p1 (outp holds slice-0 partial) ----------------
__global__ __launch_bounds__(256)
void reduce_out_kernel(const float* __restrict__ x1,
                       const float* __restrict__ p1,
                       float* outp) {
  int i = blockIdx.x * 256 + threadIdx.x;
  float4 a = ((const float4*)x1)[i];
  float4 b = ((const float4*)p1)[i];
  float4 c = ((float4*)outp)[i];
  float4 v;
  v.x = a.x + b.x + c.x; v.y = a.y + b.y + c.y;
  v.z = a.z + b.z + c.z; v.w = a.w + b.w + c.w;
  ((float4*)outp)[i] = v;
}

// ---------------- GEMM: C[M,ldc] = A[M,K] @ B[N,K]^T (m97 structure) ----------------
// EPI_QKV: Q cols (<1024) scaled by QSCALE; V cols (>=2048) redirected to VT[b,h,d][s].
template<int EPI, typename OutT, typename ResT>
__global__ __launch_bounds__(256)
void gemm_bt(const unsigned short* __restrict__ A,
             const unsigned short* __restrict__ B,
             OutT* C, const ResT* R, unsigned short* VT,
             int M, int N, int K, int ldc) {
  __shared__ __align__(16) unsigned short As[128 * 32];
  __shared__ __align__(16) unsigned short Bs[128 * 32];
  const int tid = threadIdx.x;
  const int wave = tid >> 6;
  const int lane = tid & 63;
  const int m0 = blockIdx.y * 128;
  const int n0 = blockIdx.x * 128;
  const int wm = (wave & 1) * 64;
  const int wn = (wave >> 1) * 64;
  const int frow = lane & 15;
  const int fk = (lane >> 4) * 8;

  floatx4 acc[4][4];
#pragma unroll
  for (int i = 0; i < 4; ++i)
#pragma unroll
    for (int j = 0; j < 4; ++j) acc[i][j] = (floatx4){0.f, 0.f, 0.f, 0.f};

  const int srow = lane >> 2;
  const int scol = (lane & 3) * 8;
  const unsigned short* Ag  = A + (size_t)(m0 + wave * 16 + srow) * K + scol;
  const unsigned short* Ag2 = A + (size_t)(m0 + (wave + 4) * 16 + srow) * K + scol;
  const unsigned short* Bg  = B + (size_t)(n0 + wave * 16 + srow) * K + scol;
  const unsigned short* Bg2 = B + (size_t)(n0 + (wave + 4) * 16 + srow) * K + scol;

  for (int k0 = 0; k0 < K; k0 += 32) {
    __syncthreads();
    load_lds16(Ag + k0,  &As[wave * 512]);
    load_lds16(Ag2 + k0, &As[(wave + 4) * 512]);
    load_lds16(Bg + k0,  &Bs[wave * 512]);
    load_lds16(Bg2 + k0, &Bs[(wave + 4) * 512]);
    __syncthreads();
    short8 af[4], bf[4];
#pragma unroll
    for (int i = 0; i < 4; ++i) af[i] = *(const short8*)&As[(wm + 16*i + frow)*32 + fk];
#pragma unroll
    for (int j = 0; j < 4; ++j) bf[j] = *(const short8*)&Bs[(wn + 16*j + frow)*32 + fk];
#pragma unroll
    for (int i = 0; i < 4; ++i)
#pragma unroll
      for (int j = 0; j < 4; ++j)
        acc[i][j] = __builtin_amdgcn_mfma_f32_16x16x32_bf16(af[i], bf[j], acc[i][j], 0, 0, 0);
  }

  const int g4 = (lane >> 4) * 4;

  if constexpr (EPI == EPI_QKV) {
    if (n0 >= 2048) {
      // V tile: store transposed into VT[(b*16+h)*64+dd][s]
#pragma unroll
      for (int i = 0; i < 4; ++i) {
        const int row0 = m0 + wm + 16*i + g4;     // token index (r=0)
        const int b = row0 >> 11, s0 = row0 & 2047;
#pragma unroll
        for (int j = 0; j < 4; ++j) {
          const int col = n0 + wn + 16*j + frow;  // 2048..3071
          const int dg = col - 2048;
          const int rowv = (b << 10) + dg;        // (b*16+h)*64+dd == b*1024+dg
          ushort4 ov;
          ov.x = f2b(acc[i][j][0]);
          ov.y = f2b(acc[i][j][1]);
          ov.z = f2b(acc[i][j][2]);
          ov.w = f2b(acc[i][j][3]);
          *(ushort4*)(VT + (size_t)rowv * 2048 + s0) = ov;
        }
      }
      return;
    }
  }

  const float qs = (EPI == EPI_QKV && n0 < 1024) ? QSCALE : 1.0f;
#pragma unroll
  for (int i = 0; i < 4; ++i) {
#pragma unroll
    for (int r = 0; r < 4; ++r) {
      const int row = m0 + wm + 16*i + g4 + r;
#pragma unroll
      for (int j = 0; j < 4; ++j) {
        const int col = n0 + wn + 16*j + frow;
        const size_t idx = (size_t)row * ldc + col;
        float v = acc[i][j][r];
        if constexpr (EPI == EPI_RES) {
          v += (float)R[idx];
        } else if constexpr (EPI == EPI_GATE) {
          float up = b2f((unsigned short)R[idx]);
          v = up * (v / (1.f + __expf(-v)));
        } else if constexpr (EPI == EPI_QKV) {
          v *= qs;
        }
        if constexpr (sizeof(OutT) == 4) C[idx] = v;
        else                             C[idx] = f2b(v);
      }
    }
  }
}

// ---------------- Split-K GEMM: P_z[M,N] = A[M, z*Ks : (z+1)*Ks] @ B^T slice ----------------
__global__ __launch_bounds__(256)
void gemm_bt_splitk(const unsigned short* __restrict__ A,
                    const unsigned short* __restrict__ B,
                    float* __restrict__ P0, float* __restrict__ P1,
                    int M, int N, int K, int Ks) {
  __shared__ __align__(16) unsigned short As[128 * 32];
  __shared__ __align__(16) unsigned short Bs[128 * 32];
  const int tid = threadIdx.x;
  const int wave = tid >> 6;
  const int lane = tid & 63;
  const int m0 = blockIdx.y * 128;
  const int n0 = blockIdx.x * 128;
  const int z = blockIdx.z;
  float* C = z ? P1 : P0;
  const int kbase = z * Ks;
  const int wm = (wave & 1) * 64;
  const int wn = (wave >> 1) * 64;
  const int frow = lane & 15;
  const int fk = (lane >> 4) * 8;

  floatx4 acc[4][4];
#pragma unroll
  for (int i = 0; i < 4; ++i)
#pragma unroll
    for (int j = 0; j < 4; ++j) acc[i][j] = (floatx4){0.f, 0.f, 0.f, 0.f};

  const int srow = lane >> 2;
  const int scol = (lane & 3) * 8;
  const unsigned short* Ag  = A + (size_t)(m0 + wave * 16 + srow) * K + kbase + scol;
  const unsigned short* Ag2 = A + (size_t)(m0 + (wave + 4) * 16 + srow) * K + kbase + scol;
  const unsigned short* Bg  = B + (size_t)(n0 + wave * 16 + srow) * K + kbase + scol;
  const unsigned short* Bg2 = B + (size_t)(n0 + (wave + 4) * 16 + srow) * K + kbase + scol;

  for (int k0 = 0; k0 < Ks; k0 += 32) {
    __syncthreads();
    load_lds16(Ag + k0,  &As[wave * 512]);
    load_lds16(Ag2 + k0, &As[(wave + 4) * 512]);
    load_lds16(Bg + k0,  &Bs[wave * 512]);
    load_lds16(Bg2 + k0, &Bs[(wave + 4) * 512]);
    __syncthreads();
    short8 af[4], bf[4];
#pragma unroll
    for (int i = 0; i < 4; ++i) af[i] = *(const short8*)&As[(wm + 16*i + frow)*32 + fk];
#pragma unroll
    for (int j = 0; j < 4; ++j) bf[j] = *(const short8*)&Bs[(wn + 16*j + frow)*32 + fk];
#pragma unroll
    for (int i = 0; i < 4; ++i)
#pragma unroll
      for (int j = 0; j < 4; ++j)
        acc[i][j] = __builtin_amdgcn_mfma_f32_16x16x32_bf16(af[i], bf[j], acc[i][j], 0, 0, 0);
  }

  const int g4 = (lane >> 4) * 4;
#pragma unroll
  for (int i = 0; i < 4; ++i)
#pragma unroll
    for (int r = 0; r < 4; ++r) {
      const int row = m0 + wm + 16*i + g4 + r;
#pragma unroll
      for (int j = 0; j < 4; ++j) {
        const int col = n0 + wn + 16*j + frow;
        C[(size_t)row * N + col] = acc[i][j][r];
      }
    }
}

// ================= 256x(128out) 8-phase up+gate GEMM (m201 template, T1+T2+T3+T4+T5) =======
// A [4096,1024] bf16, Bu/Bg [4096,1024] bf16; C[row*4096+col] = up * silu(gate), bf16.
// BM=256, BK=64, 8 waves (2M x 4N), per-wave 128 rows x 32 up-cols (+32 gate).
// LDS 128 KiB: A[q][h] at (q*2+h)*8192 ushorts, B[q][h] at 32768 + (q*2+h)*8192.
//   B-half0 = w_up rows [bx*128,+128), B-half1 = w_gate rows (same out cols!).
// Swizzle: LDS(row, g) holds global granule g^(row&7); read XOR matches (both-sides).
// Stage slots: ph1:(t+1).A1  ph2-5:(t+2).{A0,B0,B1,A1}  ph6-8:(t+3).{A0,B0,B1}.
// vmcnt(6) (=3 half-tiles in flight) only at ph4/ph8, before the closing barrier.

#define A_OFF(q,h) (((q)*2+(h))*8192)
#define B_OFF(q,h) (32768 + ((q)*2+(h))*8192)

#define STAGE(LB, SRC, T) do {                                               \
    const unsigned short* _s = (SRC) + (size_t)r0 * 1024 + (T) * 64 + gs;    \
    load_lds16(_s,             &lds[(LB) + wave * 512]);                     \
    load_lds16(_s + 64 * 1024, &lds[(LB) + 4096 + wave * 512]);              \
  } while (0)

#define LDA4(dst, q, h) do {                                                 \
    const unsigned short* _b = &lds[A_OFF(q,h) + arow];                      \
    _Pragma("unroll")                                                        \
    for (int _i = 0; _i < 4; ++_i) {                                         \
      dst[_i][0] = *(const short8*)(_b + _i * 1024 + g0);                    \
      dst[_i][1] = *(const short8*)(_b + _i * 1024 + g1);                    \
    }                                                                        \
  } while (0)

#define LDB2(dst, q, h) do {                                                 \
    const unsigned short* _b = &lds[B_OFF(q,h) + brow];                      \
    _Pragma("unroll")                                                        \
    for (int _j = 0; _j < 2; ++_j) {                                         \
      dst[_j][0] = *(const short8*)(_b + _j * 1024 + g0);                    \
      dst[_j][1] = *(const short8*)(_b + _j * 1024 + g1);                    \
    }                                                                        \
  } while (0)

#define MMQ(aa, bb, IO, JO) do {                                             \
    _Pragma("unroll")                                                        \
    for (int _i = 0; _i < 4; ++_i)                                           \
      _Pragma("unroll")                                                      \
      for (int _j = 0; _j < 2; ++_j) {                                       \
        acc[(IO)+_i][(JO)+_j] = __builtin_amdgcn_mfma_f32_16x16x32_bf16(     \
            aa[_i][0], bb[_j][0], acc[(IO)+_i][(JO)+_j], 0, 0, 0);           \
        acc[(IO)+_i][(JO)+_j] = __builtin_amdgcn_mfma_f32_16x16x32_bf16(     \
            aa[_i][1], bb[_j][1], acc[(IO)+_i][(JO)+_j], 0, 0, 0);           \
      }                                                                      \
  } while (0)

__global__ __launch_bounds__(512, 2)
void gemm256_upgate(const unsigned short* __restrict__ A,
                    const unsigned short* __restrict__ Bu,
                    const unsigned short* __restrict__ Bg,
                    unsigned short* __restrict__ C) {
  extern __shared__ __align__(16) unsigned short lds[];   // 65536 ushorts = 128 KiB
  const int tid  = threadIdx.x;
  const int wave = tid >> 6;
  const int lane = tid & 63;
  const int wr   = wave >> 2;       // 0..1  M-split
  const int wc   = wave & 3;        // 0..3  N-split
  const int frow = lane & 15;
  const int s4   = lane >> 4;       // 0..3

  // bijective XCD swizzle (512 % 8 == 0)
  const int orig = blockIdx.x;
  const int swz  = (orig & 7) * 64 + (orig >> 3);
  const int bx   = swz & 31;        // n-tile (out cols /128)
  const int by   = swz >> 5;        // m-tile (rows /256)
  const int m0   = by * 256;
  const int n0   = bx * 128;

  // fragment-read swizzled granule offsets (ushorts)
  const int f7 = frow & 7;
  const int g0 = ((0 + s4) ^ f7) * 8;    // kk=0
  const int g1 = ((4 + s4) ^ f7) * 8;    // kk=1
  const int arow = (wr * 64 + frow) * 64;   // + (i&3)*1024
  const int brow = (wc * 32 + frow) * 64;   // + (j&1)*1024

  // staging per-lane: LDS row r0 (+64 for round 1), pre-swizzled source granule
  const int r0 = wave * 8 + (lane >> 3);
  const int gs = ((lane & 7) ^ (lane >> 3)) * 8;

  const unsigned short* Asrc  = A  + (size_t)m0 * 1024;          // A-half1: +128*1024
  const unsigned short* B0src = Bu + (size_t)(bx * 128) * 1024;  // up rows
  const unsigned short* B1src = Bg + (size_t)(bx * 128) * 1024;  // gate rows (same cols)

  floatx4 acc[8][4];
#pragma unroll
  for (int i = 0; i < 8; ++i)
#pragma unroll
    for (int j = 0; j < 4; ++j) acc[i][j] = (floatx4){0.f, 0.f, 0.f, 0.f};

  // ---- prologue: tile0 {A0,B0,B1,A1}, vmcnt(4); tile1 {A0,B0,B1}, vmcnt(6) ----
  STAGE(A_OFF(0,0), Asrc, 0);
  STAGE(B_OFF(0,0), B0src, 0);
  STAGE(B_OFF(0,1), B1src, 0);
  STAGE(A_OFF(0,1), Asrc + 128 * 1024, 0);
  WVM(4);
  STAGE(A_OFF(1,0), Asrc, 1);
  STAGE(B_OFF(1,0), B0src, 1);
  STAGE(B_OFF(1,1), B1src, 1);
  WVM(6);
  GBAR();

  short8 af0[4][2], af1[4][2], bf0[2][2], bf1[2][2];

  for (int it = 0; it < 8; ++it) {
    const int t   = it * 2;                 // even tile -> buf0, odd -> buf1
    const int tn2 = (t + 2) & 15;           // wrapped (last iter stages are dead writes)
    const int tn3 = (t + 3) & 15;
    // ph1: (m0,n0) from buf0 | stage (t+1).A1
    LDA4(af0, 0, 0);
    LDB2(bf0, 0, 0);
    STAGE(A_OFF(1,1), Asrc + 128 * 1024, (t + 1) & 15);
    GBAR(); WLG();
    __builtin_amdgcn_s_setprio(1); MMQ(af0, bf0, 0, 0); __builtin_amdgcn_s_setprio(0);
    GBAR();
    // ph2: (m0,n1) | stage (t+2).A0
    LDB2(bf1, 0, 1);
    STAGE(A_OFF(0,0), Asrc, tn2);
    GBAR(); WLG();
    __builtin_amdgcn_s_setprio(1); MMQ(af0, bf1, 0, 2); __builtin_amdgcn_s_setprio(0);
    GBAR();
    // ph3: (m1,n0) | stage (t+2).B0
    LDA4(af1, 0, 1);
    STAGE(B_OFF(0,0), B0src, tn2);
    GBAR(); WLG();
    __builtin_amdgcn_s_setprio(1); MMQ(af1, bf0, 4, 0); __builtin_amdgcn_s_setprio(0);
    GBAR();
    // ph4: (m1,n1) | stage (t+2).B1 | vmcnt(6)
    STAGE(B_OFF(0,1), B1src, tn2);
    GBAR();
    __builtin_amdgcn_s_setprio(1); MMQ(af1, bf1, 4, 2); __builtin_amdgcn_s_setprio(0);
    WVM(6);
    GBAR();
    // ph5: (m0,n0) from buf1 | stage (t+2).A1
    LDA4(af0, 1, 0);
    LDB2(bf0, 1, 0);
    STAGE(A_OFF(0,1), Asrc + 128 * 1024, tn2);
    GBAR(); WLG();
    __builtin_amdgcn_s_setprio(1); MMQ(af0, bf0, 0, 0); __builtin_amdgcn_s_setprio(0);
    GBAR();
    // ph6: (m0,n1) | stage (t+3).A0
    LDB2(bf1, 1, 1);
    STAGE(A_OFF(1,0), Asrc, tn3);
    GBAR(); WLG();
    __builtin_amdgcn_s_setprio(1); MMQ(af0, bf1, 0, 2); __builtin_amdgcn_s_setprio(0);
    GBAR();
    // ph7: (m1,n0) | stage (t+3).B0
    LDA4(af1, 1, 1);
    STAGE(B_OFF(1,0), B0src, tn3);
    GBAR(); WLG();
    __builtin_amdgcn_s_setprio(1); MMQ(af1, bf0, 4, 0); __builtin_amdgcn_s_setprio(0);
    GBAR();
    // ph8: (m1,n1) | stage (t+3).B1 | vmcnt(6)
    STAGE(B_OFF(1,1), B1src, tn3);
    GBAR();
    __builtin_amdgcn_s_setprio(1); MMQ(af1, bf1, 4, 2); __builtin_amdgcn_s_setprio(0);
    WVM(6);
    GBAR();
  }
  asm volatile("s_waitcnt vmcnt(0)" ::: "memory");

  // ---- epilogue: v = up * silu(gate); acc[i][j] (j<2)=up, acc[i][j+2]=gate, same col ----
#pragma unroll
  for (int i = 0; i < 8; ++i) {
    const int row = m0 + (i >> 2) * 128 + wr * 64 + (i & 3) * 16 + s4 * 4;
#pragma unroll
    for (int j = 0; j < 2; ++j) {
      const int col = n0 + wc * 32 + j * 16 + frow;
#pragma unroll
      for (int r = 0; r < 4; ++r) {
        const float g = acc[i][j + 2][r];
        const float v = acc[i][j][r] * (g / (1.f + __expf(-g)));
        C[(size_t)(row + r) * 4096 + col] = f2b(v);
      }
    }
  }
}

// ---------------- Flash attention (causal), dh=64, S^T form ----------------
// 8 waves per q-tile (16 q-rows/wave): halved per-wave softmax chain, doubled TLP.
// LPT dispatch (qt descending) + 64 KB LDS -> 2 blocks/CU -> 16 waves/CU sustained.
// K/V double-buffered via global_load_lds with counted vmcnt(4); XOR-swizzled LDS;
// in-register P^T via cvt_pk-pack + v_permlane{32,16}_swap_b32.
__global__ __launch_bounds__(512, 4)
void attn_kernel(const unsigned short* __restrict__ qkv,  // [B*S, 2048] bf16: Q(scaled),K
                 const unsigned short* __restrict__ vt,   // [B*1024, 2048] bf16: V^T
                 unsigned short* __restrict__ out) {      // [B*S, 1024] bf16
  __shared__ __align__(16) unsigned short Ks[2][2][128 * 32];  // [buf][kq][key][32]: 32 KB
  __shared__ __align__(16) unsigned short Vs[2][4][64 * 32];   // [buf][c][d][32]:    32 KB
  const int lin = blockIdx.x;
  const int bh = lin & 31;
  const int qt = 15 - (lin >> 5);                    // LPT: longest blocks first
  const int b = bh >> 4, h = bh & 15;
  const int tid = threadIdx.x, w = tid >> 6, lane = tid & 63;
  const int f = lane & 15, g = lane >> 4;
  const int fk = g * 8, g4 = g * 4;
  // swizzled LDS read granule: col = g ^ ((row%16)>>1 & 3); row%16 == f for all reads
  const int fks = (g ^ ((f >> 1) & 3)) * 8;

  const unsigned short* Qb = qkv + (size_t)(b * 2048) * 2048 + h * 64;
  const unsigned short* Kb = Qb + 1024;
  const unsigned short* Vt = vt + ((size_t)(b * 16 + h) * 64) * 2048;

  const int q0 = qt * 128 + w * 16;                  // wave's 16 q rows
  short8 qf[2];
#pragma unroll
  for (int kq = 0; kq < 2; ++kq)
    qf[kq] = *(const short8*)(Qb + (size_t)(q0 + f) * 2048 + kq * 32 + fk);

  float m_s = -1e30f, l_s = 0.f;
  floatx4 o[4];
#pragma unroll
  for (int mt = 0; mt < 4; ++mt) o[mt] = (floatx4){0.f, 0.f, 0.f, 0.f};

  const int srow = lane >> 2;
  // pre-swizzled source granule: global granule (lane&3) ^ ((srow>>1)&3)
  const int scolx = ((lane & 3) ^ ((lane >> 3) & 3)) * 8;
  const int vc = w >> 1, vh = w & 1;                 // V quarter owned by this wave

  // per-wave stage: 4 x global_load_lds(16B) -> counted by WVM(4)
  auto stage = [&](int bb, int kb) {
#pragma unroll
    for (int kq = 0; kq < 2; ++kq)                   // K: seg w (16 keys)
      load_lds16(Kb + (size_t)(kb * 128 + w * 16 + srow) * 2048 + kq * 32 + scolx,
                 &Ks[bb][kq][w * 512]);
#pragma unroll
    for (int u = 0; u < 2; ++u)                      // V: c=w>>1, d-rows (w&1)*32+u*16
      load_lds16(Vt + (size_t)(vh * 32 + u * 16 + srow) * 2048 + kb * 128 + vc * 32 + scolx,
                 &Vs[bb][vc][(vh * 32 + u * 16) * 32]);
  };

  stage(0, 0);

  for (int kb = 0; kb <= qt; ++kb) {
    const int cur = kb & 1;
    GBAR();                                   // all waves done reading buf[cur^1]
    if (kb < qt) {
      stage(cur ^ 1, kb + 1);                 // prefetch next tile (in flight across compute)
      WVM(4);                                 // own buf[cur] loads (older 4) retired
    } else {
      WVM(0);
    }
    GBAR();                                   // buf[cur] complete for all waves
    __builtin_amdgcn_sched_barrier(0);

    const bool diag = (kb == qt);
    const int jhi = diag ? w : 7;             // j==w is the partial diag sub-block

    floatx4 s[8];
#pragma unroll
    for (int j = 0; j < 8; ++j) {
      if (j > jhi) continue;
      short8 kf0 = *(const short8*)&Ks[cur][0][(16*j + f) * 32 + fks];
      short8 kf1 = *(const short8*)&Ks[cur][1][(16*j + f) * 32 + fks];
      __builtin_amdgcn_s_setprio(1);
      s[j] = (floatx4){0.f, 0.f, 0.f, 0.f};
      s[j] = __builtin_amdgcn_mfma_f32_16x16x32_bf16(kf0, qf[0], s[j], 0, 0, 0);
      s[j] = __builtin_amdgcn_mfma_f32_16x16x32_bf16(kf1, qf[1], s[j], 0, 0, 0);
      __builtin_amdgcn_s_setprio(0);
    }
    if (diag) {
      // j == w sub-block: key (g4+r) > query (f) masked
#pragma unroll
      for (int j = 0; j < 8; ++j) {
        if (j != w) continue;
#pragma unroll
        for (int r = 0; r < 4; ++r)
          if (g4 + r > f) s[j][r] = -1e30f;
      }
    }
    {
      float mx = -1e30f;
#pragma unroll
      for (int j = 0; j < 8; ++j) {
        if (j > jhi) continue;
#pragma unroll
        for (int r = 0; r < 4; ++r) mx = fmaxf(mx, s[j][r]);
      }
      mx = fmaxf(mx, __shfl_xor(mx, 16));
      mx = fmaxf(mx, __shfl_xor(mx, 32));
      const float mnew = fmaxf(m_s, mx);
      const float alpha = exp2f(m_s - mnew);
      float rs = 0.f;
#pragma unroll
      for (int j = 0; j < 8; ++j) {
        if (j > jhi) continue;
#pragma unroll
        for (int r = 0; r < 4; ++r) {
          float pv = exp2f(s[j][r] - mnew);
          s[j][r] = pv;
          rs += pv;
        }
      }
      rs += __shfl_xor(rs, 16);
      rs += __shfl_xor(rs, 32);
      l_s = l_s * alpha + rs;
      m_s = mnew;
#pragma unroll
      for (int mt = 0; mt < 4; ++mt) o[mt] *= alpha;
    }

    // PV: P^T B-fragment built in-register (verified permlane construction).
    const int chi = diag ? (w >> 1) : 3;
#pragma unroll
    for (int c = 0; c < 4; ++c) {
      if (c > chi) continue;
      unsigned int P01 = f2b2(s[2*c][0], s[2*c][1]);
      unsigned int P23 = f2b2(s[2*c][2], s[2*c][3]);
      unsigned int Q01 = 0u, Q23 = 0u;
      if (2*c + 1 <= jhi) {                      // wave-uniform
        Q01 = f2b2(s[2*c+1][0], s[2*c+1][1]);
        Q23 = f2b2(s[2*c+1][2], s[2*c+1][3]);
      }
      asm("v_permlane32_swap_b32 %0, %1" : "+v"(P01), "+v"(Q01));
      asm("v_permlane32_swap_b32 %0, %1" : "+v"(P23), "+v"(Q23));
      asm("v_permlane16_swap_b32 %0, %1" : "+v"(P01), "+v"(Q01));
      asm("v_permlane16_swap_b32 %0, %1" : "+v"(P23), "+v"(Q23));
      union { unsigned int d[4]; short8 v; } pbu;
      pbu.d[0] = P01; pbu.d[1] = P23; pbu.d[2] = Q01; pbu.d[3] = Q23;
#pragma unroll
      for (int mt = 0; mt < 4; ++mt) {
        short8 va = *(const short8*)&Vs[cur][c][(16*mt + f) * 32 + fks];
        __builtin_amdgcn_s_setprio(1);
        o[mt] = __builtin_amdgcn_mfma_f32_16x16x32_bf16(va, pbu.v, o[mt], 0, 0, 0);
        __builtin_amdgcn_s_setprio(0);
      }
    }
  }

  {
    const float inv = 1.0f / l_s;
    unsigned short* orow = out + (size_t)(b * 2048 + q0 + f) * 1024 + h * 64;
#pragma unroll
    for (int mt = 0; mt < 4; ++mt) {
      ushort4 ov;
      ov.x = f2b(o[mt][0] * inv);
      ov.y = f2b(o[mt][1] * inv);
      ov.z = f2b(o[mt][2] * inv);
      ov.w = f2b(o[mt][3] * inv);
      *(ushort4*)(orow + 16 * mt + g4) = ov;
    }
  }
}

// ---------------- launcher ----------------
extern "C" void kernel_launch(void* const* d_in, const int* in_sizes, int n_in,
                              void* d_out, int out_size, void* d_ws, size_t ws_size,
                              hipStream_t stream) {
  const float* x      = (const float*)d_in[0];   // [2,2048,1024]
  const float* w_qkv  = (const float*)d_in[1];   // [3072,1024]
  const float* w_o    = (const float*)d_in[2];   // [1024,1024]
  const float* w_up   = (const float*)d_in[3];   // [4096,1024]
  const float* w_gate = (const float*)d_in[4];   // [4096,1024]
  const float* w_down = (const float*)d_in[5];   // [1024,4096]
  const float* scale1 = (const float*)d_in[6];
  const float* scale2 = (const float*)d_in[7];

  char* ws = (char*)d_ws;
  unsigned short* wq_b = (unsigned short*)(ws);                 //  6,291,456 B
  unsigned short* wo_b = (unsigned short*)(ws +  6291456);      //  2,097,152 B
  unsigned short* wu_b = (unsigned short*)(ws +  8388608);      //  8,388,608 B
  unsigned short* wg_b = (unsigned short*)(ws + 16777216);      //  8,388,608 B
  unsigned short* wd_b = (unsigned short*)(ws + 25165824);      //  8,388,608 B
  unsigned short* qkv  = (unsigned short*)(ws + 33554432);      // 16,777,216 B (Q,K; ldc 2048)
  unsigned short* hup  = (unsigned short*)(ws + 33554432);      // 33,554,432 B (aliases qkv+vT+attnb)
  unsigned short* vT   = (unsigned short*)(ws + 50331648);      //  8,388,608 B (V^T)
  unsigned short* attnb= (unsigned short*)(ws + 58720256);      //  8,388,608 B
  unsigned short* xn   = (unsigned short*)(ws + 67108864);      //  8,388,608 B
  float*          x1   = (float*)         (ws + 75497472);      // 16,777,216 B (fp32)
  float*          outp = (float*)d_out;                         // fp32

  // split-K partials (aliased over dead regions at their point of use):
  float* wo_p0   = (float*)(ws + 33554432);  // over qkv (dead after attn)
  float* wo_p1   = (float*)d_out;            // d_out unused until MLP end
  float* down_p0 = (float*)d_out;            // slice 0 -> d_out
  float* down_p1 = (float*)(ws + 8388608);   // over wu_b+wg_b (dead after upgate)

  const int M = 4096;
  dim3 blk(256);

  static int lds_opted = 0;
  if (!lds_opted) {
    (void)hipFuncSetAttribute((const void*)gemm256_upgate,
                              hipFuncAttributeMaxDynamicSharedMemorySize, 131072);
    lds_opted = 1;
  }

  // all weights fp32 -> bf16 in one dispatch (4,194,304 float4s)
  cvt_all_kernel<<<16384, blk, 0, stream>>>(w_qkv, w_o, w_up, w_gate, w_down,
                                            wq_b, wo_b, wu_b, wg_b, wd_b);

  // x1 = x + W_o( attn( rms(x) ) )    [W_o via split-K, reduce fused into rmsnorm_res2]
  rmsnorm_kernel<<<4096, blk, 0, stream>>>(x, scale1, xn);
  gemm_bt<EPI_QKV, unsigned short, unsigned short>
      <<<dim3(24, 32), blk, 0, stream>>>(xn, wq_b, qkv, (const unsigned short*)nullptr, vT,
                                         M, 3072, 1024, 2048);
  attn_kernel<<<dim3(512), dim3(512), 0, stream>>>(qkv, vT, attnb);
  gemm_bt_splitk<<<dim3(8, 32, 2), blk, 0, stream>>>(attnb, wo_b, wo_p0, wo_p1,
                                                     M, 1024, 1024, 512);

  // x1 = x + p0 + p1 ; xn = rms(x1)
  rmsnorm_res2_kernel<<<4096, blk, 0, stream>>>(x, wo_p0, wo_p1, scale2, x1, xn);

  // out = x1 + W_down( up(rms) * silu(gate(rms)) )   [W_down via split-K]
  gemm256_upgate<<<dim3(512), dim3(512), 131072, stream>>>(xn, wu_b, wg_b, hup);
  gemm_bt_splitk<<<dim3(8, 32, 2), blk, 0, stream>>>(hup, wd_b, down_p0, down_p1,
                                                     M, 1024, 4096, 2048);
  reduce_out_kernel<<<4096, blk, 0, stream>>>(x1, down_p1, outp);

  (void)in_sizes; (void)n_in; (void)out_size; (void)ws_size;
}

// Round 7
// 357.403 us; speedup vs baseline: 1.3352x; 1.0758x over previous
//
#include <hip/hip_runtime.h>

// TransformerBlock: x = x + attn(rms(x)); x = x + mlp(rms(x))
// B=2, S=2048, D=1024, H=16, dh=64, EXP=4. Inputs/outputs fp32; internal bf16 MFMA.

typedef __attribute__((ext_vector_type(8))) short short8;   // 8 x bf16 = 4 VGPR
typedef __attribute__((ext_vector_type(4))) float floatx4;  // MFMA 16x16 acc

#define EPI_NONE 0
#define EPI_RES  1
#define EPI_GATE 2
#define EPI_QKV  3

#define QSCALE 0.1803368801f   // 0.125 * log2(e): folded into Q so softmax is base-2

__device__ __forceinline__ float b2f(unsigned short u) {
  union { unsigned int i; float f; } c; c.i = ((unsigned int)u) << 16; return c.f;
}
__device__ __forceinline__ unsigned short f2b(float f) {
  union { float f; unsigned int u; } c; c.f = f;
  unsigned int r = 0x7fffu + ((c.u >> 16) & 1u);
  return (unsigned short)((c.u + r) >> 16);
}
__device__ __forceinline__ unsigned int f2b2(float a, float b) {
  return (unsigned int)f2b(a) | ((unsigned int)f2b(b) << 16);
}

__device__ __forceinline__ void load_lds16(const void* g, void* l) {
  __builtin_amdgcn_global_load_lds(
      (const __attribute__((address_space(1))) unsigned int*)g,
      (__attribute__((address_space(3))) unsigned int*)l, 16, 0, 0);
}

#define GBAR() __builtin_amdgcn_s_barrier()
#define WLG()  asm volatile("s_waitcnt lgkmcnt(0)" ::: "memory")
#define WVM(N) asm volatile("s_waitcnt vmcnt(" #N ")" ::: "memory")

// ---------------- fused fp32 -> bf16 convert of all 5 weights ----------------
// float4 units: wq 786432, wo 262144, wu/wg/wd 1048576 each; total 4194304.
__global__ __launch_bounds__(256)
void cvt_all_kernel(const float* __restrict__ wq, const float* __restrict__ wo,
                    const float* __restrict__ wu, const float* __restrict__ wg,
                    const float* __restrict__ wd,
                    unsigned short* __restrict__ oq, unsigned short* __restrict__ oo,
                    unsigned short* __restrict__ ou, unsigned short* __restrict__ og,
                    unsigned short* __restrict__ od) {
  int i = blockIdx.x * 256 + threadIdx.x;
  const float* src; unsigned short* dst; int k;
  if (i < 786432)        { src = wq; dst = oq; k = i; }
  else if (i < 1048576)  { src = wo; dst = oo; k = i - 786432; }
  else if (i < 2097152)  { src = wu; dst = ou; k = i - 1048576; }
  else if (i < 3145728)  { src = wg; dst = og; k = i - 2097152; }
  else                   { src = wd; dst = od; k = i - 3145728; }
  float4 v = ((const float4*)src)[k];
  ushort4 o;
  o.x = f2b(v.x); o.y = f2b(v.y); o.z = f2b(v.z); o.w = f2b(v.w);
  ((ushort4*)dst)[k] = o;
}

// ---------------- RMSNorm: one block per row of 1024, fp32 in -> bf16 out ----------------
__global__ __launch_bounds__(256)
void rmsnorm_kernel(const float* __restrict__ x,
                    const float* __restrict__ scale,
                    unsigned short* __restrict__ y) {
  const int row = blockIdx.x;
  const int tid = threadIdx.x;
  const int base = row * 1024 + tid * 4;
  float4 v = *(const float4*)(x + base);
  float ss = v.x*v.x + v.y*v.y + v.z*v.z + v.w*v.w;
#pragma unroll
  for (int d = 32; d > 0; d >>= 1) ss += __shfl_down(ss, d);
  __shared__ float red[4];
  const int wave = tid >> 6, lane = tid & 63;
  if (lane == 0) red[wave] = ss;
  __syncthreads();
  float tot = red[0] + red[1] + red[2] + red[3];
  float rs = rsqrtf(tot * (1.0f/1024.0f) + 1e-6f);
  float4 sv = *(const float4*)(scale + tid * 4);
  ushort4 o;
  o.x = f2b(v.x * rs * sv.x);
  o.y = f2b(v.y * rs * sv.y);
  o.z = f2b(v.z * rs * sv.z);
  o.w = f2b(v.w * rs * sv.w);
  *(ushort4*)(y + base) = o;
}

// ---------------- RMSNorm + residual reduce: x1 = x + p0 + p1; y = rms(x1) ----------------
__global__ __launch_bounds__(256)
void rmsnorm_res2_kernel(const float* __restrict__ x,
                         const float* __restrict__ p0,
                         const float* __restrict__ p1,
                         const float* __restrict__ scale,
                         float* __restrict__ x1,
                         unsigned short* __restrict__ y) {
  const int row = blockIdx.x;
  const int tid = threadIdx.x;
  const int base = row * 1024 + tid * 4;
  float4 a = *(const float4*)(x + base);
  float4 b = *(const float4*)(p0 + base);
  float4 c = *(const float4*)(p1 + base);
  float4 v;
  v.x = a.x + b.x + c.x; v.y = a.y + b.y + c.y;
  v.z = a.z + b.z + c.z; v.w = a.w + b.w + c.w;
  *(float4*)(x1 + base) = v;
  float ss = v.x*v.x + v.y*v.y + v.z*v.z + v.w*v.w;
#pragma unroll
  for (int d = 32; d > 0; d >>= 1) ss += __shfl_down(ss, d);
  __shared__ float red[4];
  const int wave = tid >> 6, lane = tid & 63;
  if (lane == 0) red[wave] = ss;
  __syncthreads();
  float tot = red[0] + red[1] + red[2] + red[3];
  float rs = rsqrtf(tot * (1.0f/1024.0f) + 1e-6f);
  float4 sv = *(const float4*)(scale + tid * 4);
  ushort4 o;
  o.x = f2b(v.x * rs * sv.x);
  o.y = f2b(v.y * rs * sv.y);
  o.z = f2b(v.z * rs * sv.z);
  o.w = f2b(v.w * rs * sv.w);
  *(ushort4*)(y + base) = o;
}

// ---------------- final reduce: outp = x1 + outp + p1 (outp holds slice-0 partial) ----------------
__global__ __launch_bounds__(256)
void reduce_out_kernel(const float* __restrict__ x1,
                       const float* __restrict__ p1,
                       float* outp) {
  int i = blockIdx.x * 256 + threadIdx.x;
  float4 a = ((const float4*)x1)[i];
  float4 b = ((const float4*)p1)[i];
  float4 c = ((float4*)outp)[i];
  float4 v;
  v.x = a.x + b.x + c.x; v.y = a.y + b.y + c.y;
  v.z = a.z + b.z + c.z; v.w = a.w + b.w + c.w;
  ((float4*)outp)[i] = v;
}

// ---------------- GEMM: C[M,ldc] = A[M,K] @ B[N,K]^T (m97 structure) ----------------
// EPI_QKV: Q cols (<1024) scaled by QSCALE; V cols (>=2048) redirected to VT[b,h,d][s].
template<int EPI, typename OutT, typename ResT>
__global__ __launch_bounds__(256)
void gemm_bt(const unsigned short* __restrict__ A,
             const unsigned short* __restrict__ B,
             OutT* C, const ResT* R, unsigned short* VT,
             int M, int N, int K, int ldc) {
  __shared__ __align__(16) unsigned short As[128 * 32];
  __shared__ __align__(16) unsigned short Bs[128 * 32];
  const int tid = threadIdx.x;
  const int wave = tid >> 6;
  const int lane = tid & 63;
  const int m0 = blockIdx.y * 128;
  const int n0 = blockIdx.x * 128;
  const int wm = (wave & 1) * 64;
  const int wn = (wave >> 1) * 64;
  const int frow = lane & 15;
  const int fk = (lane >> 4) * 8;

  floatx4 acc[4][4];
#pragma unroll
  for (int i = 0; i < 4; ++i)
#pragma unroll
    for (int j = 0; j < 4; ++j) acc[i][j] = (floatx4){0.f, 0.f, 0.f, 0.f};

  const int srow = lane >> 2;
  const int scol = (lane & 3) * 8;
  const unsigned short* Ag  = A + (size_t)(m0 + wave * 16 + srow) * K + scol;
  const unsigned short* Ag2 = A + (size_t)(m0 + (wave + 4) * 16 + srow) * K + scol;
  const unsigned short* Bg  = B + (size_t)(n0 + wave * 16 + srow) * K + scol;
  const unsigned short* Bg2 = B + (size_t)(n0 + (wave + 4) * 16 + srow) * K + scol;

  for (int k0 = 0; k0 < K; k0 += 32) {
    __syncthreads();
    load_lds16(Ag + k0,  &As[wave * 512]);
    load_lds16(Ag2 + k0, &As[(wave + 4) * 512]);
    load_lds16(Bg + k0,  &Bs[wave * 512]);
    load_lds16(Bg2 + k0, &Bs[(wave + 4) * 512]);
    __syncthreads();
    short8 af[4], bf[4];
#pragma unroll
    for (int i = 0; i < 4; ++i) af[i] = *(const short8*)&As[(wm + 16*i + frow)*32 + fk];
#pragma unroll
    for (int j = 0; j < 4; ++j) bf[j] = *(const short8*)&Bs[(wn + 16*j + frow)*32 + fk];
#pragma unroll
    for (int i = 0; i < 4; ++i)
#pragma unroll
      for (int j = 0; j < 4; ++j)
        acc[i][j] = __builtin_amdgcn_mfma_f32_16x16x32_bf16(af[i], bf[j], acc[i][j], 0, 0, 0);
  }

  const int g4 = (lane >> 4) * 4;

  if constexpr (EPI == EPI_QKV) {
    if (n0 >= 2048) {
      // V tile: store transposed into VT[(b*16+h)*64+dd][s]
#pragma unroll
      for (int i = 0; i < 4; ++i) {
        const int row0 = m0 + wm + 16*i + g4;     // token index (r=0)
        const int b = row0 >> 11, s0 = row0 & 2047;
#pragma unroll
        for (int j = 0; j < 4; ++j) {
          const int col = n0 + wn + 16*j + frow;  // 2048..3071
          const int dg = col - 2048;
          const int rowv = (b << 10) + dg;        // (b*16+h)*64+dd == b*1024+dg
          ushort4 ov;
          ov.x = f2b(acc[i][j][0]);
          ov.y = f2b(acc[i][j][1]);
          ov.z = f2b(acc[i][j][2]);
          ov.w = f2b(acc[i][j][3]);
          *(ushort4*)(VT + (size_t)rowv * 2048 + s0) = ov;
        }
      }
      return;
    }
  }

  const float qs = (EPI == EPI_QKV && n0 < 1024) ? QSCALE : 1.0f;
#pragma unroll
  for (int i = 0; i < 4; ++i) {
#pragma unroll
    for (int r = 0; r < 4; ++r) {
      const int row = m0 + wm + 16*i + g4 + r;
#pragma unroll
      for (int j = 0; j < 4; ++j) {
        const int col = n0 + wn + 16*j + frow;
        const size_t idx = (size_t)row * ldc + col;
        float v = acc[i][j][r];
        if constexpr (EPI == EPI_RES) {
          v += (float)R[idx];
        } else if constexpr (EPI == EPI_GATE) {
          float up = b2f((unsigned short)R[idx]);
          v = up * (v / (1.f + __expf(-v)));
        } else if constexpr (EPI == EPI_QKV) {
          v *= qs;
        }
        if constexpr (sizeof(OutT) == 4) C[idx] = v;
        else                             C[idx] = f2b(v);
      }
    }
  }
}

// ---------------- Split-K GEMM: P_z[M,N] = A[M, z*Ks : (z+1)*Ks] @ B^T slice ----------------
__global__ __launch_bounds__(256)
void gemm_bt_splitk(const unsigned short* __restrict__ A,
                    const unsigned short* __restrict__ B,
                    float* __restrict__ P0, float* __restrict__ P1,
                    int M, int N, int K, int Ks) {
  __shared__ __align__(16) unsigned short As[128 * 32];
  __shared__ __align__(16) unsigned short Bs[128 * 32];
  const int tid = threadIdx.x;
  const int wave = tid >> 6;
  const int lane = tid & 63;
  const int m0 = blockIdx.y * 128;
  const int n0 = blockIdx.x * 128;
  const int z = blockIdx.z;
  float* C = z ? P1 : P0;
  const int kbase = z * Ks;
  const int wm = (wave & 1) * 64;
  const int wn = (wave >> 1) * 64;
  const int frow = lane & 15;
  const int fk = (lane >> 4) * 8;

  floatx4 acc[4][4];
#pragma unroll
  for (int i = 0; i < 4; ++i)
#pragma unroll
    for (int j = 0; j < 4; ++j) acc[i][j] = (floatx4){0.f, 0.f, 0.f, 0.f};

  const int srow = lane >> 2;
  const int scol = (lane & 3) * 8;
  const unsigned short* Ag  = A + (size_t)(m0 + wave * 16 + srow) * K + kbase + scol;
  const unsigned short* Ag2 = A + (size_t)(m0 + (wave + 4) * 16 + srow) * K + kbase + scol;
  const unsigned short* Bg  = B + (size_t)(n0 + wave * 16 + srow) * K + kbase + scol;
  const unsigned short* Bg2 = B + (size_t)(n0 + (wave + 4) * 16 + srow) * K + kbase + scol;

  for (int k0 = 0; k0 < Ks; k0 += 32) {
    __syncthreads();
    load_lds16(Ag + k0,  &As[wave * 512]);
    load_lds16(Ag2 + k0, &As[(wave + 4) * 512]);
    load_lds16(Bg + k0,  &Bs[wave * 512]);
    load_lds16(Bg2 + k0, &Bs[(wave + 4) * 512]);
    __syncthreads();
    short8 af[4], bf[4];
#pragma unroll
    for (int i = 0; i < 4; ++i) af[i] = *(const short8*)&As[(wm + 16*i + frow)*32 + fk];
#pragma unroll
    for (int j = 0; j < 4; ++j) bf[j] = *(const short8*)&Bs[(wn + 16*j + frow)*32 + fk];
#pragma unroll
    for (int i = 0; i < 4; ++i)
#pragma unroll
      for (int j = 0; j < 4; ++j)
        acc[i][j] = __builtin_amdgcn_mfma_f32_16x16x32_bf16(af[i], bf[j], acc[i][j], 0, 0, 0);
  }

  const int g4 = (lane >> 4) * 4;
#pragma unroll
  for (int i = 0; i < 4; ++i)
#pragma unroll
    for (int r = 0; r < 4; ++r) {
      const int row = m0 + wm + 16*i + g4 + r;
#pragma unroll
      for (int j = 0; j < 4; ++j) {
        const int col = n0 + wn + 16*j + frow;
        C[(size_t)row * N + col] = acc[i][j][r];
      }
    }
}

// ================= 256-tile 8-phase GEMM machinery (m201 template) =================
#define A_OFF(q,h) (((q)*2+(h))*8192)
#define B_OFF(q,h) (32768 + ((q)*2+(h))*8192)
#define BD_OFF(q)  (32768 + (q)*8192)

#define STAGE_S(LB, SRC, T, STR) do {                                        \
    const unsigned short* _s = (SRC) + (size_t)r0 * (STR) + (T) * 64 + gs;   \
    load_lds16(_s,                    &lds[(LB) + wave * 512]);              \
    load_lds16(_s + (size_t)64*(STR), &lds[(LB) + 4096 + wave * 512]);       \
  } while (0)

#define STAGE(LB, SRC, T) STAGE_S(LB, SRC, T, 1024)

#define LDA4X(dst, BASE) do {                                                \
    const unsigned short* _b = &lds[(BASE) + arow];                          \
    _Pragma("unroll")                                                        \
    for (int _i = 0; _i < 4; ++_i) {                                         \
      dst[_i][0] = *(const short8*)(_b + _i * 1024 + g0);                    \
      dst[_i][1] = *(const short8*)(_b + _i * 1024 + g1);                    \
    }                                                                        \
  } while (0)

#define LDB2X(dst, BASE) do {                                                \
    const unsigned short* _b = &lds[(BASE) + brow];                          \
    _Pragma("unroll")                                                        \
    for (int _j = 0; _j < 2; ++_j) {                                         \
      dst[_j][0] = *(const short8*)(_b + _j * 1024 + g0);                    \
      dst[_j][1] = *(const short8*)(_b + _j * 1024 + g1);                    \
    }                                                                        \
  } while (0)

#define LDA4(dst, q, h) LDA4X(dst, A_OFF(q,h))
#define LDB2(dst, q, h) LDB2X(dst, B_OFF(q,h))

#define MMQ(aa, bb, IO, JO) do {                                             \
    _Pragma("unroll")                                                        \
    for (int _i = 0; _i < 4; ++_i)                                           \
      _Pragma("unroll")                                                      \
      for (int _j = 0; _j < 2; ++_j) {                                       \
        acc[(IO)+_i][(JO)+_j] = __builtin_amdgcn_mfma_f32_16x16x32_bf16(     \
            aa[_i][0], bb[_j][0], acc[(IO)+_i][(JO)+_j], 0, 0, 0);           \
        acc[(IO)+_i][(JO)+_j] = __builtin_amdgcn_mfma_f32_16x16x32_bf16(     \
            aa[_i][1], bb[_j][1], acc[(IO)+_i][(JO)+_j], 0, 0, 0);           \
      }                                                                      \
  } while (0)

// ---- 256x128 8-phase up+gate GEMM. XCD chunking: each XCD owns an 8x8 tile chunk ----
__global__ __launch_bounds__(512, 2)
void gemm256_upgate(const unsigned short* __restrict__ A,
                    const unsigned short* __restrict__ Bu,
                    const unsigned short* __restrict__ Bg,
                    unsigned short* __restrict__ C) {
  extern __shared__ __align__(16) unsigned short lds[];   // 65536 ushorts = 128 KiB
  const int tid  = threadIdx.x;
  const int wave = tid >> 6;
  const int lane = tid & 63;
  const int wr   = wave >> 2;       // 0..1  M-split
  const int wc   = wave & 3;        // 0..3  N-split
  const int frow = lane & 15;
  const int s4   = lane >> 4;       // 0..3

  // XCD 8x8 chunk swizzle (512 blocks, 64/XCD): L2 working set A 4MB + B 4MB,
  // each line shared by 8 co-resident blocks (was: 2 by x all bx -> B streamed 16MB/XCD).
  const int orig = blockIdx.x;
  const int xcd  = orig & 7, l = orig >> 3;       // l in [0,64)
  const int by   = (xcd >> 2) * 8 + (l >> 3);     // 0..15
  const int bx   = (xcd & 3) * 8 + (l & 7);       // 0..31
  const int m0   = by * 256;
  const int n0   = bx * 128;

  // fragment-read swizzled granule offsets (ushorts)
  const int f7 = frow & 7;
  const int g0 = ((0 + s4) ^ f7) * 8;    // kk=0
  const int g1 = ((4 + s4) ^ f7) * 8;    // kk=1
  const int arow = (wr * 64 + frow) * 64;   // + (i&3)*1024
  const int brow = (wc * 32 + frow) * 64;   // + (j&1)*1024

  // staging per-lane: LDS row r0 (+64 for round 1), pre-swizzled source granule
  const int r0 = wave * 8 + (lane >> 3);
  const int gs = ((lane & 7) ^ (lane >> 3)) * 8;

  const unsigned short* Asrc  = A  + (size_t)m0 * 1024;          // A-half1: +128*1024
  const unsigned short* B0src = Bu + (size_t)(bx * 128) * 1024;  // up rows
  const unsigned short* B1src = Bg + (size_t)(bx * 128) * 1024;  // gate rows (same cols)

  floatx4 acc[8][4];
#pragma unroll
  for (int i = 0; i < 8; ++i)
#pragma unroll
    for (int j = 0; j < 4; ++j) acc[i][j] = (floatx4){0.f, 0.f, 0.f, 0.f};

  // ---- prologue: tile0 {A0,B0,B1,A1}, vmcnt(4); tile1 {A0,B0,B1}, vmcnt(6) ----
  STAGE(A_OFF(0,0), Asrc, 0);
  STAGE(B_OFF(0,0), B0src, 0);
  STAGE(B_OFF(0,1), B1src, 0);
  STAGE(A_OFF(0,1), Asrc + 128 * 1024, 0);
  WVM(4);
  STAGE(A_OFF(1,0), Asrc, 1);
  STAGE(B_OFF(1,0), B0src, 1);
  STAGE(B_OFF(1,1), B1src, 1);
  WVM(6);
  GBAR();

  short8 af0[4][2], af1[4][2], bf0[2][2], bf1[2][2];

  for (int it = 0; it < 8; ++it) {
    const int t   = it * 2;                 // even tile -> buf0, odd -> buf1
    const int tn2 = (t + 2) & 15;           // wrapped (last iter stages are dead writes)
    const int tn3 = (t + 3) & 15;
    // ph1: (m0,n0) from buf0 | stage (t+1).A1
    LDA4(af0, 0, 0);
    LDB2(bf0, 0, 0);
    STAGE(A_OFF(1,1), Asrc + 128 * 1024, (t + 1) & 15);
    GBAR(); WLG();
    __builtin_amdgcn_s_setprio(1); MMQ(af0, bf0, 0, 0); __builtin_amdgcn_s_setprio(0);
    GBAR();
    // ph2: (m0,n1) | stage (t+2).A0
    LDB2(bf1, 0, 1);
    STAGE(A_OFF(0,0), Asrc, tn2);
    GBAR(); WLG();
    __builtin_amdgcn_s_setprio(1); MMQ(af0, bf1, 0, 2); __builtin_amdgcn_s_setprio(0);
    GBAR();
    // ph3: (m1,n0) | stage (t+2).B0
    LDA4(af1, 0, 1);
    STAGE(B_OFF(0,0), B0src, tn2);
    GBAR(); WLG();
    __builtin_amdgcn_s_setprio(1); MMQ(af1, bf0, 4, 0); __builtin_amdgcn_s_setprio(0);
    GBAR();
    // ph4: (m1,n1) | stage (t+2).B1 | vmcnt(6)
    STAGE(B_OFF(0,1), B1src, tn2);
    GBAR();
    __builtin_amdgcn_s_setprio(1); MMQ(af1, bf1, 4, 2); __builtin_amdgcn_s_setprio(0);
    WVM(6);
    GBAR();
    // ph5: (m0,n0) from buf1 | stage (t+2).A1
    LDA4(af0, 1, 0);
    LDB2(bf0, 1, 0);
    STAGE(A_OFF(0,1), Asrc + 128 * 1024, tn2);
    GBAR(); WLG();
    __builtin_amdgcn_s_setprio(1); MMQ(af0, bf0, 0, 0); __builtin_amdgcn_s_setprio(0);
    GBAR();
    // ph6: (m0,n1) | stage (t+3).A0
    LDB2(bf1, 1, 1);
    STAGE(A_OFF(1,0), Asrc, tn3);
    GBAR(); WLG();
    __builtin_amdgcn_s_setprio(1); MMQ(af0, bf1, 0, 2); __builtin_amdgcn_s_setprio(0);
    GBAR();
    // ph7: (m1,n0) | stage (t+3).B0
    LDA4(af1, 1, 1);
    STAGE(B_OFF(1,0), B0src, tn3);
    GBAR(); WLG();
    __builtin_amdgcn_s_setprio(1); MMQ(af1, bf0, 4, 0); __builtin_amdgcn_s_setprio(0);
    GBAR();
    // ph8: (m1,n1) | stage (t+3).B1 | vmcnt(6)
    STAGE(B_OFF(1,1), B1src, tn3);
    GBAR();
    __builtin_amdgcn_s_setprio(1); MMQ(af1, bf1, 4, 2); __builtin_amdgcn_s_setprio(0);
    WVM(6);
    GBAR();
  }
  asm volatile("s_waitcnt vmcnt(0)" ::: "memory");

  // ---- epilogue: v = up * silu(gate); acc[i][j] (j<2)=up, acc[i][j+2]=gate, same col ----
#pragma unroll
  for (int i = 0; i < 8; ++i) {
    const int row = m0 + (i >> 2) * 128 + wr * 64 + (i & 3) * 16 + s4 * 4;
#pragma unroll
    for (int j = 0; j < 2; ++j) {
      const int col = n0 + wc * 32 + j * 16 + frow;
#pragma unroll
      for (int r = 0; r < 4; ++r) {
        const float g = acc[i][j + 2][r];
        const float v = acc[i][j][r] * (g / (1.f + __expf(-g)));
        C[(size_t)(row + r) * 4096 + col] = f2b(v);
      }
    }
  }
}

// ---- 256x128 4-phase split-K down GEMM: P_z = hup[:, z*2048:+2048] @ wd_slice^T ----
// A = hup [4096,4096] bf16, B = wd [1024,4096] bf16 (row = out col). BM=256, BN=128,
// BK=64, 8 waves (2M x 4N, per-wave 128x32). LDS 96 KiB: A 2x2x8192, B 2x8192.
// Stage slots/iter: ph1:(t+1).A1  ph2:(t+2).{A0,B}  ph3:(t+2).A1  ph4:(t+3).{A0,B}.
//   Safety: every region staged >=1 barrier after its last read (A00:r@ph1/s@ph2,
//   B0:r@ph1/s@ph2, A01:r@ph2/s@ph3, A10:r@ph3/s@ph4, B1:r@ph3/s@ph4, A11:r@ph4/s@ph1').
//   WVM(4)@ph2-end: (t+1).A1 retired (4 newer loads = ph2's stages) before ph3/ph4 read buf1.
//   WVM(4)@ph4-end: (t+2).{A0,B,A1} retired before next ph1/ph2 read buf0.
// Grid 256 = 1 block/CU. XCD chunk: 2 by x 8 bx x 2 z per XCD -> hup read once.
__global__ __launch_bounds__(512, 2)
void gemm256_down(const unsigned short* __restrict__ A,
                  const unsigned short* __restrict__ B,
                  float* __restrict__ P0, float* __restrict__ P1) {
  extern __shared__ __align__(16) unsigned short lds[];   // 49152 ushorts = 96 KiB
  const int tid  = threadIdx.x;
  const int wave = tid >> 6;
  const int lane = tid & 63;
  const int wr   = wave >> 2;
  const int wc   = wave & 3;
  const int frow = lane & 15;
  const int s4   = lane >> 4;

  const int orig = blockIdx.x;
  const int xcd  = orig & 7, l = orig >> 3;       // l in [0,32)
  const int z    = l & 1;
  const int by   = xcd * 2 + ((l >> 1) & 1);      // 0..15
  const int bx   = l >> 2;                        // 0..7
  const int m0   = by * 256;
  const int n0   = bx * 128;
  float* P = z ? P1 : P0;

  const int f7 = frow & 7;
  const int g0 = ((0 + s4) ^ f7) * 8;
  const int g1 = ((4 + s4) ^ f7) * 8;
  const int arow = (wr * 64 + frow) * 64;
  const int brow = (wc * 32 + frow) * 64;
  const int r0 = wave * 8 + (lane >> 3);
  const int gs = ((lane & 7) ^ (lane >> 3)) * 8;

  const unsigned short* Asrc = A + (size_t)m0 * 4096 + z * 2048;
  const unsigned short* Bsrc = B + (size_t)n0 * 4096 + z * 2048;

  floatx4 acc[8][2];
#pragma unroll
  for (int i = 0; i < 8; ++i)
#pragma unroll
    for (int j = 0; j < 2; ++j) acc[i][j] = (floatx4){0.f, 0.f, 0.f, 0.f};

  // prologue: t0.{A0,B,A1} then t1.{A0,B}; WVM(4) -> t0 complete
  STAGE_S(A_OFF(0,0), Asrc, 0, 4096);
  STAGE_S(BD_OFF(0),  Bsrc, 0, 4096);
  STAGE_S(A_OFF(0,1), Asrc + (size_t)128 * 4096, 0, 4096);
  STAGE_S(A_OFF(1,0), Asrc, 1, 4096);
  STAGE_S(BD_OFF(1),  Bsrc, 1, 4096);
  WVM(4);
  GBAR();

  short8 af0[4][2], af1[4][2], bf[2][2];

  for (int it = 0; it < 16; ++it) {
    const int t   = it * 2;
    const int tn2 = (t + 2) & 31;
    const int tn3 = (t + 3) & 31;
    // ph1: buf0 m-half0 | stage (t+1).A1
    LDA4(af0, 0, 0);
    LDB2X(bf, BD_OFF(0));
    STAGE_S(A_OFF(1,1), Asrc + (size_t)128 * 4096, (t + 1) & 31, 4096);
    GBAR(); WLG();
    __builtin_amdgcn_s_setprio(1); MMQ(af0, bf, 0, 0); __builtin_amdgcn_s_setprio(0);
    GBAR();
    // ph2: buf0 m-half1 | stage (t+2).A0, (t+2).B | WVM(4)
    LDA4(af1, 0, 1);
    STAGE_S(A_OFF(0,0), Asrc, tn2, 4096);
    STAGE_S(BD_OFF(0),  Bsrc, tn2, 4096);
    GBAR(); WLG();
    __builtin_amdgcn_s_setprio(1); MMQ(af1, bf, 4, 0); __builtin_amdgcn_s_setprio(0);
    WVM(4);
    GBAR();
    // ph3: buf1 m-half0 | stage (t+2).A1
    LDA4(af0, 1, 0);
    LDB2X(bf, BD_OFF(1));
    STAGE_S(A_OFF(0,1), Asrc + (size_t)128 * 4096, tn2, 4096);
    GBAR(); WLG();
    __builtin_amdgcn_s_setprio(1); MMQ(af0, bf, 0, 0); __builtin_amdgcn_s_setprio(0);
    GBAR();
    // ph4: buf1 m-half1 | stage (t+3).A0, (t+3).B | WVM(4)
    LDA4(af1, 1, 1);
    STAGE_S(A_OFF(1,0), Asrc, tn3, 4096);
    STAGE_S(BD_OFF(1),  Bsrc, tn3, 4096);
    GBAR(); WLG();
    __builtin_amdgcn_s_setprio(1); MMQ(af1, bf, 4, 0); __builtin_amdgcn_s_setprio(0);
    WVM(4);
    GBAR();
  }
  asm volatile("s_waitcnt vmcnt(0)" ::: "memory");

#pragma unroll
  for (int i = 0; i < 8; ++i) {
    const int row = m0 + (i >> 2) * 128 + wr * 64 + (i & 3) * 16 + s4 * 4;
#pragma unroll
    for (int j = 0; j < 2; ++j) {
      const int col = n0 + wc * 32 + j * 16 + frow;
#pragma unroll
      for (int r = 0; r < 4; ++r)
        P[(size_t)(row + r) * 1024 + col] = acc[i][j][r];
    }
  }
}

// ---------------- Flash attention (causal), dh=64, S^T form ----------------
// 8 waves per q-tile (16 q-rows/wave); LPT dispatch; 64 KB LDS -> 2 blocks/CU.
// K/V double-buffered global_load_lds with counted vmcnt(4); XOR-swizzled LDS;
// in-register P^T via cvt_pk-pack + v_permlane{32,16}_swap_b32.
__global__ __launch_bounds__(512, 4)
void attn_kernel(const unsigned short* __restrict__ qkv,  // [B*S, 2048] bf16: Q(scaled),K
                 const unsigned short* __restrict__ vt,   // [B*1024, 2048] bf16: V^T
                 unsigned short* __restrict__ out) {      // [B*S, 1024] bf16
  __shared__ __align__(16) unsigned short Ks[2][2][128 * 32];  // [buf][kq][key][32]: 32 KB
  __shared__ __align__(16) unsigned short Vs[2][4][64 * 32];   // [buf][c][d][32]:    32 KB
  const int lin = blockIdx.x;
  const int bh = lin & 31;
  const int qt = 15 - (lin >> 5);                    // LPT: longest blocks first
  const int b = bh >> 4, h = bh & 15;
  const int tid = threadIdx.x, w = tid >> 6, lane = tid & 63;
  const int f = lane & 15, g = lane >> 4;
  const int fk = g * 8, g4 = g * 4;
  const int fks = (g ^ ((f >> 1) & 3)) * 8;

  const unsigned short* Qb = qkv + (size_t)(b * 2048) * 2048 + h * 64;
  const unsigned short* Kb = Qb + 1024;
  const unsigned short* Vt = vt + ((size_t)(b * 16 + h) * 64) * 2048;

  const int q0 = qt * 128 + w * 16;                  // wave's 16 q rows
  short8 qf[2];
#pragma unroll
  for (int kq = 0; kq < 2; ++kq)
    qf[kq] = *(const short8*)(Qb + (size_t)(q0 + f) * 2048 + kq * 32 + fk);

  float m_s = -1e30f, l_s = 0.f;
  floatx4 o[4];
#pragma unroll
  for (int mt = 0; mt < 4; ++mt) o[mt] = (floatx4){0.f, 0.f, 0.f, 0.f};

  const int srow = lane >> 2;
  const int scolx = ((lane & 3) ^ ((lane >> 3) & 3)) * 8;
  const int vc = w >> 1, vh = w & 1;                 // V quarter owned by this wave

  auto stage = [&](int bb, int kb) {
#pragma unroll
    for (int kq = 0; kq < 2; ++kq)                   // K: seg w (16 keys)
      load_lds16(Kb + (size_t)(kb * 128 + w * 16 + srow) * 2048 + kq * 32 + scolx,
                 &Ks[bb][kq][w * 512]);
#pragma unroll
    for (int u = 0; u < 2; ++u)                      // V: c=w>>1, d-rows (w&1)*32+u*16
      load_lds16(Vt + (size_t)(vh * 32 + u * 16 + srow) * 2048 + kb * 128 + vc * 32 + scolx,
                 &Vs[bb][vc][(vh * 32 + u * 16) * 32]);
  };

  stage(0, 0);

  for (int kb = 0; kb <= qt; ++kb) {
    const int cur = kb & 1;
    GBAR();
    if (kb < qt) {
      stage(cur ^ 1, kb + 1);
      WVM(4);
    } else {
      WVM(0);
    }
    GBAR();
    __builtin_amdgcn_sched_barrier(0);

    const bool diag = (kb == qt);
    const int jhi = diag ? w : 7;

    floatx4 s[8];
#pragma unroll
    for (int j = 0; j < 8; ++j) {
      if (j > jhi) continue;
      short8 kf0 = *(const short8*)&Ks[cur][0][(16*j + f) * 32 + fks];
      short8 kf1 = *(const short8*)&Ks[cur][1][(16*j + f) * 32 + fks];
      __builtin_amdgcn_s_setprio(1);
      s[j] = (floatx4){0.f, 0.f, 0.f, 0.f};
      s[j] = __builtin_amdgcn_mfma_f32_16x16x32_bf16(kf0, qf[0], s[j], 0, 0, 0);
      s[j] = __builtin_amdgcn_mfma_f32_16x16x32_bf16(kf1, qf[1], s[j], 0, 0, 0);
      __builtin_amdgcn_s_setprio(0);
    }
    if (diag) {
#pragma unroll
      for (int j = 0; j < 8; ++j) {
        if (j != w) continue;
#pragma unroll
        for (int r = 0; r < 4; ++r)
          if (g4 + r > f) s[j][r] = -1e30f;
      }
    }
    {
      float mx = -1e30f;
#pragma unroll
      for (int j = 0; j < 8; ++j) {
        if (j > jhi) continue;
#pragma unroll
        for (int r = 0; r < 4; ++r) mx = fmaxf(mx, s[j][r]);
      }
      mx = fmaxf(mx, __shfl_xor(mx, 16));
      mx = fmaxf(mx, __shfl_xor(mx, 32));
      const float mnew = fmaxf(m_s, mx);
      const float alpha = exp2f(m_s - mnew);
      float rs = 0.f;
#pragma unroll
      for (int j = 0; j < 8; ++j) {
        if (j > jhi) continue;
#pragma unroll
        for (int r = 0; r < 4; ++r) {
          float pv = exp2f(s[j][r] - mnew);
          s[j][r] = pv;
          rs += pv;
        }
      }
      rs += __shfl_xor(rs, 16);
      rs += __shfl_xor(rs, 32);
      l_s = l_s * alpha + rs;
      m_s = mnew;
#pragma unroll
      for (int mt = 0; mt < 4; ++mt) o[mt] *= alpha;
    }

    const int chi = diag ? (w >> 1) : 3;
#pragma unroll
    for (int c = 0; c < 4; ++c) {
      if (c > chi) continue;
      unsigned int P01 = f2b2(s[2*c][0], s[2*c][1]);
      unsigned int P23 = f2b2(s[2*c][2], s[2*c][3]);
      unsigned int Q01 = 0u, Q23 = 0u;
      if (2*c + 1 <= jhi) {
        Q01 = f2b2(s[2*c+1][0], s[2*c+1][1]);
        Q23 = f2b2(s[2*c+1][2], s[2*c+1][3]);
      }
      asm("v_permlane32_swap_b32 %0, %1" : "+v"(P01), "+v"(Q01));
      asm("v_permlane32_swap_b32 %0, %1" : "+v"(P23), "+v"(Q23));
      asm("v_permlane16_swap_b32 %0, %1" : "+v"(P01), "+v"(Q01));
      asm("v_permlane16_swap_b32 %0, %1" : "+v"(P23), "+v"(Q23));
      union { unsigned int d[4]; short8 v; } pbu;
      pbu.d[0] = P01; pbu.d[1] = P23; pbu.d[2] = Q01; pbu.d[3] = Q23;
#pragma unroll
      for (int mt = 0; mt < 4; ++mt) {
        short8 va = *(const short8*)&Vs[cur][c][(16*mt + f) * 32 + fks];
        __builtin_amdgcn_s_setprio(1);
        o[mt] = __builtin_amdgcn_mfma_f32_16x16x32_bf16(va, pbu.v, o[mt], 0, 0, 0);
        __builtin_amdgcn_s_setprio(0);
      }
    }
  }

  {
    const float inv = 1.0f / l_s;
    unsigned short* orow = out + (size_t)(b * 2048 + q0 + f) * 1024 + h * 64;
#pragma unroll
    for (int mt = 0; mt < 4; ++mt) {
      ushort4 ov;
      ov.x = f2b(o[mt][0] * inv);
      ov.y = f2b(o[mt][1] * inv);
      ov.z = f2b(o[mt][2] * inv);
      ov.w = f2b(o[mt][3] * inv);
      *(ushort4*)(orow + 16 * mt + g4) = ov;
    }
  }
}

// ---------------- launcher ----------------
extern "C" void kernel_launch(void* const* d_in, const int* in_sizes, int n_in,
                              void* d_out, int out_size, void* d_ws, size_t ws_size,
                              hipStream_t stream) {
  const float* x      = (const float*)d_in[0];   // [2,2048,1024]
  const float* w_qkv  = (const float*)d_in[1];   // [3072,1024]
  const float* w_o    = (const float*)d_in[2];   // [1024,1024]
  const float* w_up   = (const float*)d_in[3];   // [4096,1024]
  const float* w_gate = (const float*)d_in[4];   // [4096,1024]
  const float* w_down = (const float*)d_in[5];   // [1024,4096]
  const float* scale1 = (const float*)d_in[6];
  const float* scale2 = (const float*)d_in[7];

  char* ws = (char*)d_ws;
  unsigned short* wq_b = (unsigned short*)(ws);                 //  6,291,456 B
  unsigned short* wo_b = (unsigned short*)(ws +  6291456);      //  2,097,152 B
  unsigned short* wu_b = (unsigned short*)(ws +  8388608);      //  8,388,608 B
  unsigned short* wg_b = (unsigned short*)(ws + 16777216);      //  8,388,608 B
  unsigned short* wd_b = (unsigned short*)(ws + 25165824);      //  8,388,608 B
  unsigned short* qkv  = (unsigned short*)(ws + 33554432);      // 16,777,216 B (Q,K; ldc 2048)
  unsigned short* hup  = (unsigned short*)(ws + 33554432);      // 33,554,432 B (aliases qkv+vT+attnb)
  unsigned short* vT   = (unsigned short*)(ws + 50331648);      //  8,388,608 B (V^T)
  unsigned short* attnb= (unsigned short*)(ws + 58720256);      //  8,388,608 B
  unsigned short* xn   = (unsigned short*)(ws + 67108864);      //  8,388,608 B
  float*          x1   = (float*)         (ws + 75497472);      // 16,777,216 B (fp32)
  float*          outp = (float*)d_out;                         // fp32

  // split-K partials (aliased over dead regions at their point of use):
  float* wo_p0   = (float*)(ws + 33554432);  // over qkv (dead after attn)
  float* wo_p1   = (float*)d_out;            // d_out unused until MLP end
  float* down_p0 = (float*)d_out;            // slice 0 -> d_out
  float* down_p1 = (float*)(ws + 8388608);   // over wu_b+wg_b (dead after upgate)

  const int M = 4096;
  dim3 blk(256);

  static int lds_opted = 0;
  if (!lds_opted) {
    (void)hipFuncSetAttribute((const void*)gemm256_upgate,
                              hipFuncAttributeMaxDynamicSharedMemorySize, 131072);
    (void)hipFuncSetAttribute((const void*)gemm256_down,
                              hipFuncAttributeMaxDynamicSharedMemorySize, 98304);
    lds_opted = 1;
  }

  // all weights fp32 -> bf16 in one dispatch (4,194,304 float4s)
  cvt_all_kernel<<<16384, blk, 0, stream>>>(w_qkv, w_o, w_up, w_gate, w_down,
                                            wq_b, wo_b, wu_b, wg_b, wd_b);

  // x1 = x + W_o( attn( rms(x) ) )    [W_o via split-K, reduce fused into rmsnorm_res2]
  rmsnorm_kernel<<<4096, blk, 0, stream>>>(x, scale1, xn);
  gemm_bt<EPI_QKV, unsigned short, unsigned short>
      <<<dim3(24, 32), blk, 0, stream>>>(xn, wq_b, qkv, (const unsigned short*)nullptr, vT,
                                         M, 3072, 1024, 2048);
  attn_kernel<<<dim3(512), dim3(512), 0, stream>>>(qkv, vT, attnb);
  gemm_bt_splitk<<<dim3(8, 32, 2), blk, 0, stream>>>(attnb, wo_b, wo_p0, wo_p1,
                                                     M, 1024, 1024, 512);

  // x1 = x + p0 + p1 ; xn = rms(x1)
  rmsnorm_res2_kernel<<<4096, blk, 0, stream>>>(x, wo_p0, wo_p1, scale2, x1, xn);

  // out = x1 + W_down( up(rms) * silu(gate(rms)) )   [W_down via 256-tile split-K]
  gemm256_upgate<<<dim3(512), dim3(512), 131072, stream>>>(xn, wu_b, wg_b, hup);
  gemm256_down<<<dim3(256), dim3(512), 98304, stream>>>(hup, wd_b, down_p0, down_p1);
  reduce_out_kernel<<<4096, blk, 0, stream>>>(x1, down_p1, outp);

  (void)in_sizes; (void)n_in; (void)out_size; (void)ws_size;
}